// Round 1
// baseline (2173.287 us; speedup 1.0000x reference)
//
#include <hip/hip_runtime.h>
#include <math.h>

#define NNODES 50000
#define NEG_SLOPE 0.2f
#define BN_EPS 1e-5f

static __device__ __forceinline__ float leaky(float x) {
    return x > 0.f ? x : NEG_SLOPE * x;
}
// float atomic max via int/uint compare trick (valid for all IEEE f32, init -inf)
static __device__ __forceinline__ void atomicMaxF(float* addr, float val) {
    if (val >= 0.f) atomicMax((int*)addr, __float_as_int(val));
    else            atomicMin((unsigned int*)addr, __float_as_uint(val));
}

// ---------------- degree ----------------
__global__ void k_deg_init(float* deg, int n) {
    int v = blockIdx.x * blockDim.x + threadIdx.x;
    if (v < n) deg[v] = 1.0f;  // self-loop
}
__global__ void k_deg_edge(const int* __restrict__ dst, float* deg, int E) {
    int e = blockIdx.x * blockDim.x + threadIdx.x;
    if (e < E) atomicAdd(&deg[dst[e]], 1.0f);
}
__global__ void k_dinv(float* deg, int n) {
    int v = blockIdx.x * blockDim.x + threadIdx.x;
    if (v < n) deg[v] = rsqrtf(deg[v]);  // deg >= 1 always
}

// ---------------- dense GEMM  C[n,Ko] = A[n,Ki] @ W[Ki,Ko] ----------------
__global__ void k_gemm(const float* __restrict__ A, const float* __restrict__ W,
                       float* __restrict__ C, int n, int Ki, int Ko) {
    int t = blockIdx.x * blockDim.x + threadIdx.x;
    if (t >= n * Ko) return;
    int row = t / Ko, col = t % Ko;
    const float* a = A + (long long)row * Ki;
    float acc = 0.f;
#pragma unroll 8
    for (int k = 0; k < Ki; ++k) acc += a[k] * W[k * Ko + col];
    C[t] = acc;
}

// ---------------- GCN scatter ----------------
// out[v,c] = dinv[v]^2 * h[v,c]   (self-loop term + accumulator init)
__global__ void k_gcn_init(const float* __restrict__ h, const float* __restrict__ dinv,
                           float* __restrict__ out, int n, int C) {
    int t = blockIdx.x * blockDim.x + threadIdx.x;
    if (t >= n * C) return;
    int v = t / C;
    float di = dinv[v];
    out[t] = di * di * h[t];
}
__global__ void k_gcn_edge(const float* __restrict__ h, const int* __restrict__ src,
                           const int* __restrict__ dst, const float* __restrict__ dinv,
                           float* out, int E, int C) {
    int t = blockIdx.x * blockDim.x + threadIdx.x;
    if (t >= E * C) return;
    int e = t / C, c = t % C;
    int s = src[e], d = dst[e];
    atomicAdd(&out[d * C + c], dinv[s] * dinv[d] * h[s * C + c]);
}

// bias + eval-BN + relu
__global__ void k_bias_bn_relu(const float* __restrict__ in, float* __restrict__ out,
                               const float* __restrict__ bias, const float* __restrict__ g,
                               const float* __restrict__ b, const float* __restrict__ m,
                               const float* __restrict__ v, int n, int C) {
    int t = blockIdx.x * blockDim.x + threadIdx.x;
    if (t >= n * C) return;
    int c = t % C;
    float x = in[t] + bias[c];
    x = (x - m[c]) * rsqrtf(v[c] + BN_EPS) * g[c] + b[c];
    out[t] = fmaxf(x, 0.f);
}

// ---------------- GAT ----------------
// per (node, head) attention logits:  alS[v,h] = <h[v,h,:], a_src[h,:]>
__global__ void k_gat_logits(const float* __restrict__ h, const float* __restrict__ as,
                             const float* __restrict__ ad, float* __restrict__ alS,
                             float* __restrict__ alD, int n, int H, int C) {
    int t = blockIdx.x * blockDim.x + threadIdx.x;
    if (t >= n * H) return;
    int hh = t % H;
    const float* row = h + (long long)t * C;  // t = v*H + hh, layout [N, H*C]
    float s1 = 0.f, s2 = 0.f;
    for (int c = 0; c < C; ++c) {
        float x = row[c];
        s1 += x * as[hh * C + c];
        s2 += x * ad[hh * C + c];
    }
    alS[t] = s1; alD[t] = s2;
}
// mx = self-loop logit (every segment contains its self-loop), denom = 0
__global__ void k_gat_init(const float* __restrict__ alS, const float* __restrict__ alD,
                           float* __restrict__ mx, float* __restrict__ denom, int nH) {
    int t = blockIdx.x * blockDim.x + threadIdx.x;
    if (t >= nH) return;
    mx[t] = leaky(alS[t] + alD[t]);
    denom[t] = 0.f;
}
__global__ void k_gat_max(const int* __restrict__ src, const int* __restrict__ dst,
                          const float* __restrict__ alS, const float* __restrict__ alD,
                          float* mx, int E, int H) {
    int t = blockIdx.x * blockDim.x + threadIdx.x;
    if (t >= E * H) return;
    int h = t % H, e = t / H;
    int s = src[e], d = dst[e];
    atomicMaxF(&mx[d * H + h], leaky(alS[s * H + h] + alD[d * H + h]));
}
__global__ void k_gat_exp(const int* __restrict__ src, const int* __restrict__ dst,
                          const float* __restrict__ alS, const float* __restrict__ alD,
                          const float* __restrict__ mx, float* __restrict__ eex,
                          float* denom, int E, int H) {
    int t = blockIdx.x * blockDim.x + threadIdx.x;
    if (t >= E * H) return;
    int h = t % H, e = t / H;
    int s = src[e], d = dst[e];
    float ex = expf(leaky(alS[s * H + h] + alD[d * H + h]) - mx[d * H + h]);
    eex[t] = ex;
    atomicAdd(&denom[d * H + h], ex);
}
// self-loop denom contribution (runs after edge pass; plain add)
__global__ void k_gat_self_denom(const float* __restrict__ alS, const float* __restrict__ alD,
                                 const float* __restrict__ mx, float* denom, int nH) {
    int t = blockIdx.x * blockDim.x + threadIdx.x;
    if (t >= nH) return;
    denom[t] += expf(leaky(alS[t] + alD[t]) - mx[t]);
}
// accumulator init = self-loop term: out[v,h,c] = alpha_self * h[v,h,c]
__global__ void k_gat_out_init(const float* __restrict__ hin, const float* __restrict__ alS,
                               const float* __restrict__ alD, const float* __restrict__ mx,
                               const float* __restrict__ denom, float* __restrict__ out,
                               int n, int H, int C) {
    int t = blockIdx.x * blockDim.x + threadIdx.x;
    if (t >= n * H * C) return;
    int vh = t / C;  // v*H + h
    float alpha = expf(leaky(alS[vh] + alD[vh]) - mx[vh]) / denom[vh];
    out[t] = alpha * hin[t];
}
__global__ void k_gat_edge_out(const float* __restrict__ hin, const int* __restrict__ src,
                               const int* __restrict__ dst, const float* __restrict__ eex,
                               const float* __restrict__ denom, float* out,
                               int E, int H, int C) {
    int t = blockIdx.x * blockDim.x + threadIdx.x;
    if (t >= E * H * C) return;
    int c = t % C;
    int eh = t / C;      // e*H + h
    int h = eh % H, e = eh / H;
    int s = src[e], d = dst[e];
    float alpha = eex[eh] / denom[d * H + h];
    atomicAdd(&out[(d * H + h) * C + c], alpha * hin[(s * H + h) * C + c]);
}
// head mean + bias (+ optional relu)
__global__ void k_gat_post(const float* __restrict__ acc, const float* __restrict__ bias,
                           float* __restrict__ out, int n, int H, int C, int do_relu) {
    int t = blockIdx.x * blockDim.x + threadIdx.x;
    if (t >= n * C) return;
    int v = t / C, c = t % C;
    float s = 0.f;
    for (int h = 0; h < H; ++h) s += acc[(v * H + h) * C + c];
    float x = s / (float)H + bias[c];
    out[t] = do_relu ? fmaxf(x, 0.f) : x;
}

// fused: head-mean + bias + log_softmax over 40 classes
__global__ void k_final(const float* __restrict__ acc, const float* __restrict__ bias,
                        float* __restrict__ out, int n) {
    int v = blockIdx.x * blockDim.x + threadIdx.x;
    if (v >= n) return;
    float vals[40];
    float mx = -INFINITY;
#pragma unroll
    for (int c = 0; c < 40; ++c) {
        float x = 0.5f * (acc[v * 80 + c] + acc[v * 80 + 40 + c]) + bias[c];
        vals[c] = x;
        mx = fmaxf(mx, x);
    }
    float s = 0.f;
#pragma unroll
    for (int c = 0; c < 40; ++c) s += expf(vals[c] - mx);
    float ls = logf(s);
#pragma unroll
    for (int c = 0; c < 40; ++c) out[v * 40 + c] = vals[c] - mx - ls;
}

static inline int nblk(long long n, int b) { return (int)((n + b - 1) / b); }

extern "C" void kernel_launch(void* const* d_in, const int* in_sizes, int n_in,
                              void* d_out, int out_size, void* d_ws, size_t ws_size,
                              hipStream_t stream) {
    const float* x       = (const float*)d_in[0];
    const int*   ei      = (const int*)d_in[1];
    const float* gcn1_W  = (const float*)d_in[2];
    const float* gcn1_b  = (const float*)d_in[3];
    const float* bn1_g   = (const float*)d_in[4];
    const float* bn1_b   = (const float*)d_in[5];
    const float* bn1_m   = (const float*)d_in[6];
    const float* bn1_v   = (const float*)d_in[7];
    const float* gat1_W  = (const float*)d_in[8];
    const float* gat1_as = (const float*)d_in[9];
    const float* gat1_ad = (const float*)d_in[10];
    const float* gat1_b  = (const float*)d_in[11];
    const float* gcn2_W  = (const float*)d_in[12];
    const float* gcn2_b  = (const float*)d_in[13];
    const float* bn2_g   = (const float*)d_in[14];
    const float* bn2_b   = (const float*)d_in[15];
    const float* bn2_m   = (const float*)d_in[16];
    const float* bn2_v   = (const float*)d_in[17];
    const float* gat2_W  = (const float*)d_in[18];
    const float* gat2_as = (const float*)d_in[19];
    const float* gat2_ad = (const float*)d_in[20];
    const float* gat2_b  = (const float*)d_in[21];

    const int n = NNODES;
    const int E = in_sizes[1] / 2;
    const int* src = ei;
    const int* dst = ei + E;

    // workspace layout (floats)
    float* w = (float*)d_ws;
    float* dinv  = w;                    // N
    float* bufA  = dinv + 50048;         // N*192
    float* bufB  = bufA + 9600000;       // N*192
    float* alS   = bufB + 9600000;       // N*2
    float* alD   = alS + 100000;         // N*2
    float* mx    = alD + 100000;         // N*2
    float* denom = mx + 100000;          // N*2
    float* eex   = denom + 100000;       // E*2

    const int B = 256;
    float* out = (float*)d_out;

    // ---- degree / dinv (shared by both GCN layers) ----
    k_deg_init<<<nblk(n, B), B, 0, stream>>>(dinv, n);
    k_deg_edge<<<nblk(E, B), B, 0, stream>>>(dst, dinv, E);
    k_dinv<<<nblk(n, B), B, 0, stream>>>(dinv, n);

    // ---- GCN1: x[N,128] @ W[128,96] -> scatter -> +b, BN1, relu ----
    k_gemm<<<nblk((long long)n * 96, B), B, 0, stream>>>(x, gcn1_W, bufB, n, 128, 96);
    k_gcn_init<<<nblk((long long)n * 96, B), B, 0, stream>>>(bufB, dinv, bufA, n, 96);
    k_gcn_edge<<<nblk((long long)E * 96, B), B, 0, stream>>>(bufB, src, dst, dinv, bufA, E, 96);
    k_bias_bn_relu<<<nblk((long long)n * 96, B), B, 0, stream>>>(bufA, bufB, gcn1_b,
                                                                 bn1_g, bn1_b, bn1_m, bn1_v, n, 96);

    // ---- GAT1: h[N,96] @ W[96,192], H=2, C=96 ----
    k_gemm<<<nblk((long long)n * 192, B), B, 0, stream>>>(bufB, gat1_W, bufA, n, 96, 192);
    k_gat_logits<<<nblk(n * 2, B), B, 0, stream>>>(bufA, gat1_as, gat1_ad, alS, alD, n, 2, 96);
    k_gat_init<<<nblk(n * 2, B), B, 0, stream>>>(alS, alD, mx, denom, n * 2);
    k_gat_max<<<nblk((long long)E * 2, B), B, 0, stream>>>(src, dst, alS, alD, mx, E, 2);
    k_gat_exp<<<nblk((long long)E * 2, B), B, 0, stream>>>(src, dst, alS, alD, mx, eex, denom, E, 2);
    k_gat_self_denom<<<nblk(n * 2, B), B, 0, stream>>>(alS, alD, mx, denom, n * 2);
    k_gat_out_init<<<nblk((long long)n * 192, B), B, 0, stream>>>(bufA, alS, alD, mx, denom, bufB, n, 2, 96);
    k_gat_edge_out<<<nblk((long long)E * 192, B), B, 0, stream>>>(bufA, src, dst, eex, denom, bufB, E, 2, 96);
    k_gat_post<<<nblk((long long)n * 96, B), B, 0, stream>>>(bufB, gat1_b, bufA, n, 2, 96, 1);

    // ---- GCN2: h[N,96] @ W[96,96] -> scatter -> +b, BN2, relu ----
    k_gemm<<<nblk((long long)n * 96, B), B, 0, stream>>>(bufA, gcn2_W, bufB, n, 96, 96);
    k_gcn_init<<<nblk((long long)n * 96, B), B, 0, stream>>>(bufB, dinv, bufA, n, 96);
    k_gcn_edge<<<nblk((long long)E * 96, B), B, 0, stream>>>(bufB, src, dst, dinv, bufA, E, 96);
    k_bias_bn_relu<<<nblk((long long)n * 96, B), B, 0, stream>>>(bufA, bufB, gcn2_b,
                                                                 bn2_g, bn2_b, bn2_m, bn2_v, n, 96);

    // ---- GAT2: h[N,96] @ W[96,80], H=2, C=40 ----
    k_gemm<<<nblk((long long)n * 80, B), B, 0, stream>>>(bufB, gat2_W, bufA, n, 96, 80);
    k_gat_logits<<<nblk(n * 2, B), B, 0, stream>>>(bufA, gat2_as, gat2_ad, alS, alD, n, 2, 40);
    k_gat_init<<<nblk(n * 2, B), B, 0, stream>>>(alS, alD, mx, denom, n * 2);
    k_gat_max<<<nblk((long long)E * 2, B), B, 0, stream>>>(src, dst, alS, alD, mx, E, 2);
    k_gat_exp<<<nblk((long long)E * 2, B), B, 0, stream>>>(src, dst, alS, alD, mx, eex, denom, E, 2);
    k_gat_self_denom<<<nblk(n * 2, B), B, 0, stream>>>(alS, alD, mx, denom, n * 2);
    k_gat_out_init<<<nblk((long long)n * 80, B), B, 0, stream>>>(bufA, alS, alD, mx, denom, bufB, n, 2, 40);
    k_gat_edge_out<<<nblk((long long)E * 80, B), B, 0, stream>>>(bufA, src, dst, eex, denom, bufB, E, 2, 40);

    // ---- head mean + bias + log_softmax -> d_out ----
    k_final<<<nblk(n, B), B, 0, stream>>>(bufB, gat2_b, out, n);
}

// Round 2
// 1266.363 us; speedup vs baseline: 1.7162x; 1.7162x over previous
//
#include <hip/hip_runtime.h>
#include <math.h>

#define NNODES 50000
#define NEG_SLOPE 0.2f
#define BN_EPS 1e-5f

static __device__ __forceinline__ float leaky(float x) {
    return x > 0.f ? x : NEG_SLOPE * x;
}

// ---------------- CSR build ----------------
__global__ void k_zero_deg(int* degi, int n) {
    int v = blockIdx.x * blockDim.x + threadIdx.x;
    if (v < n) degi[v] = 0;
}
__global__ void k_count(const int* __restrict__ dst, int* degi, int E) {
    int e = blockIdx.x * blockDim.x + threadIdx.x;
    if (e < E) atomicAdd(&degi[dst[e]], 1);
}
__global__ void k_dinv(const int* __restrict__ degi, float* dinv, int n) {
    int v = blockIdx.x * blockDim.x + threadIdx.x;
    if (v < n) dinv[v] = rsqrtf((float)(degi[v] + 1));  // +1 self-loop
}
// single-block scan: row_ptr[v+1] = inclusive sum, cursor[v] = exclusive
__global__ void k_scan(const int* __restrict__ degi, int* __restrict__ row_ptr,
                       int* __restrict__ cursor, int n) {
    __shared__ int sdata[1024];
    __shared__ int carry;
    if (threadIdx.x == 0) { carry = 0; row_ptr[0] = 0; }
    __syncthreads();
    for (int base = 0; base < n; base += 1024) {
        int i = base + (int)threadIdx.x;
        int v = (i < n) ? degi[i] : 0;
        sdata[threadIdx.x] = v;
        __syncthreads();
        for (int off = 1; off < 1024; off <<= 1) {
            int t = (threadIdx.x >= (unsigned)off) ? sdata[threadIdx.x - off] : 0;
            __syncthreads();
            sdata[threadIdx.x] += t;
            __syncthreads();
        }
        int incl = sdata[threadIdx.x] + carry;
        if (i < n) {
            row_ptr[i + 1] = incl;
            cursor[i] = incl - v;
        }
        __syncthreads();
        if (threadIdx.x == 1023) carry = incl;
        __syncthreads();
    }
}
__global__ void k_fill(const int* __restrict__ src, const int* __restrict__ dst,
                       int* cursor, int* __restrict__ csr_src, int E) {
    int e = blockIdx.x * blockDim.x + threadIdx.x;
    if (e >= E) return;
    int pos = atomicAdd(&cursor[dst[e]], 1);
    csr_src[pos] = src[e];
}

// ---------------- dense GEMM  C[n,Ko] = A[n,Ki] @ W[Ki,Ko] ----------------
__global__ void k_gemm(const float* __restrict__ A, const float* __restrict__ W,
                       float* __restrict__ C, int n, int Ki, int Ko) {
    int t = blockIdx.x * blockDim.x + threadIdx.x;
    if (t >= n * Ko) return;
    int row = t / Ko, col = t % Ko;
    const float* a = A + (long long)row * Ki;
    float acc = 0.f;
#pragma unroll 8
    for (int k = 0; k < Ki; ++k) acc += a[k] * W[k * Ko + col];
    C[t] = acc;
}

// ---------------- GCN gather + bias + BN + relu ----------------
__global__ void k_gcn_gather_bn(const float* __restrict__ hin, const int* __restrict__ row_ptr,
                                const int* __restrict__ csr_src, const float* __restrict__ dinv,
                                const float* __restrict__ bias, const float* __restrict__ g,
                                const float* __restrict__ b, const float* __restrict__ m,
                                const float* __restrict__ vv,
                                float* __restrict__ out, int n, int C) {
    int t = blockIdx.x * blockDim.x + threadIdx.x;
    if (t >= n * C) return;
    int v = t / C, c = t % C;
    int beg = row_ptr[v], end = row_ptr[v + 1];
    float acc = dinv[v] * hin[t];
    for (int p = beg; p < end; ++p) {
        int s = csr_src[p];
        acc += dinv[s] * hin[s * C + c];
    }
    float x = acc * dinv[v] + bias[c];
    x = (x - m[c]) * rsqrtf(vv[c] + BN_EPS) * g[c] + b[c];
    out[t] = fmaxf(x, 0.f);
}

// ---------------- GAT ----------------
// per (node, head) logits
__global__ void k_gat_logits(const float* __restrict__ h, const float* __restrict__ as,
                             const float* __restrict__ ad, float* __restrict__ alS,
                             float* __restrict__ alD, int n, int H, int C) {
    int t = blockIdx.x * blockDim.x + threadIdx.x;
    if (t >= n * H) return;
    int hh = t % H;
    const float* row = h + (long long)t * C;  // layout [N, H, C]
    float s1 = 0.f, s2 = 0.f;
    for (int c = 0; c < C; ++c) {
        float x = row[c];
        s1 += x * as[hh * C + c];
        s2 += x * ad[hh * C + c];
    }
    alS[t] = s1; alD[t] = s2;
}
// per (node, head): two-pass softmax over in-edges; eex in CSR order
__global__ void k_gat_vh(const int* __restrict__ row_ptr, const int* __restrict__ csr_src,
                         const float* __restrict__ alS, const float* __restrict__ alD,
                         float* __restrict__ eex, float* __restrict__ selfw,
                         float* __restrict__ invden, int n, int H) {
    int t = blockIdx.x * blockDim.x + threadIdx.x;
    if (t >= n * H) return;
    int v = t / H, h = t % H;
    int beg = row_ptr[v], end = row_ptr[v + 1];
    float ad = alD[t];
    float l_self = leaky(alS[t] + ad);
    float mx = l_self;
    for (int p = beg; p < end; ++p) {
        int s = csr_src[p];
        mx = fmaxf(mx, leaky(alS[s * H + h] + ad));
    }
    float exs = expf(l_self - mx);
    float den = exs;
    for (int p = beg; p < end; ++p) {
        int s = csr_src[p];
        float ex = expf(leaky(alS[s * H + h] + ad) - mx);
        eex[p * H + h] = ex;
        den += ex;
    }
    selfw[t] = exs;
    invden[t] = 1.f / den;
}
// H=2 gather + head-mean + bias (+relu)
__global__ void k_gat_gather2(const float* __restrict__ hin, const int* __restrict__ row_ptr,
                              const int* __restrict__ csr_src, const float* __restrict__ eex,
                              const float* __restrict__ selfw, const float* __restrict__ invden,
                              const float* __restrict__ bias, float* __restrict__ out,
                              int n, int C, int do_relu) {
    int t = blockIdx.x * blockDim.x + threadIdx.x;
    if (t >= n * C) return;
    int v = t / C, c = t % C;
    int beg = row_ptr[v], end = row_ptr[v + 1];
    int HC = 2 * C;
    float a0 = selfw[v * 2]     * hin[(long long)v * HC + c];
    float a1 = selfw[v * 2 + 1] * hin[(long long)v * HC + C + c];
    for (int p = beg; p < end; ++p) {
        int s = csr_src[p];
        const float* hr = hin + (long long)s * HC;
        a0 += eex[p * 2]     * hr[c];
        a1 += eex[p * 2 + 1] * hr[C + c];
    }
    float x = 0.5f * (a0 * invden[v * 2] + a1 * invden[v * 2 + 1]) + bias[c];
    out[t] = do_relu ? fmaxf(x, 0.f) : x;
}

// log_softmax over 40 classes, input [N,40] already mean+biased
__global__ void k_logsoftmax40(const float* __restrict__ in, float* __restrict__ out, int n) {
    int v = blockIdx.x * blockDim.x + threadIdx.x;
    if (v >= n) return;
    float vals[40];
    float mx = -INFINITY;
#pragma unroll
    for (int c = 0; c < 40; ++c) {
        float x = in[v * 40 + c];
        vals[c] = x;
        mx = fmaxf(mx, x);
    }
    float s = 0.f;
#pragma unroll
    for (int c = 0; c < 40; ++c) s += expf(vals[c] - mx);
    float ls = logf(s);
#pragma unroll
    for (int c = 0; c < 40; ++c) out[v * 40 + c] = vals[c] - mx - ls;
}

static inline int nblk(long long n, int b) { return (int)((n + b - 1) / b); }

extern "C" void kernel_launch(void* const* d_in, const int* in_sizes, int n_in,
                              void* d_out, int out_size, void* d_ws, size_t ws_size,
                              hipStream_t stream) {
    const float* x       = (const float*)d_in[0];
    const int*   ei      = (const int*)d_in[1];
    const float* gcn1_W  = (const float*)d_in[2];
    const float* gcn1_b  = (const float*)d_in[3];
    const float* bn1_g   = (const float*)d_in[4];
    const float* bn1_b   = (const float*)d_in[5];
    const float* bn1_m   = (const float*)d_in[6];
    const float* bn1_v   = (const float*)d_in[7];
    const float* gat1_W  = (const float*)d_in[8];
    const float* gat1_as = (const float*)d_in[9];
    const float* gat1_ad = (const float*)d_in[10];
    const float* gat1_b  = (const float*)d_in[11];
    const float* gcn2_W  = (const float*)d_in[12];
    const float* gcn2_b  = (const float*)d_in[13];
    const float* bn2_g   = (const float*)d_in[14];
    const float* bn2_b   = (const float*)d_in[15];
    const float* bn2_m   = (const float*)d_in[16];
    const float* bn2_v   = (const float*)d_in[17];
    const float* gat2_W  = (const float*)d_in[18];
    const float* gat2_as = (const float*)d_in[19];
    const float* gat2_ad = (const float*)d_in[20];
    const float* gat2_b  = (const float*)d_in[21];

    const int n = NNODES;
    const int E = in_sizes[1] / 2;
    const int* src = ei;
    const int* dst = ei + E;

    // ---- workspace carve (bytes) ----
    char* p = (char*)d_ws;
    float* dinv    = (float*)p; p += 50048 * 4;
    int*   degi    = (int*)p;   p += 50048 * 4;
    int*   row_ptr = (int*)p;   p += 50052 * 4;
    int*   cursor  = (int*)p;   p += 50048 * 4;
    int*   csr_src = (int*)p;   p += 800000 * 4;
    float* bufA    = (float*)p; p += 9600000 * 4;
    float* bufB    = (float*)p; p += 9600000 * 4;
    float* alS     = (float*)p; p += 100096 * 4;
    float* alD     = (float*)p; p += 100096 * 4;
    float* selfw   = (float*)p; p += 100096 * 4;
    float* invden  = (float*)p; p += 100096 * 4;
    float* eex     = (float*)p; p += 1600000 * 4;

    const int B = 256;
    float* out = (float*)d_out;

    // ---- CSR build (shared by all 4 graph layers) ----
    k_zero_deg<<<nblk(n, B), B, 0, stream>>>(degi, n);
    k_count<<<nblk(E, B), B, 0, stream>>>(dst, degi, E);
    k_dinv<<<nblk(n, B), B, 0, stream>>>(degi, dinv, n);
    k_scan<<<1, 1024, 0, stream>>>(degi, row_ptr, cursor, n);
    k_fill<<<nblk(E, B), B, 0, stream>>>(src, dst, cursor, csr_src, E);

    // ---- GCN1: x[N,128] @ W[128,96] -> gather -> +b, BN1, relu ----
    k_gemm<<<nblk((long long)n * 96, B), B, 0, stream>>>(x, gcn1_W, bufB, n, 128, 96);
    k_gcn_gather_bn<<<nblk((long long)n * 96, B), B, 0, stream>>>(
        bufB, row_ptr, csr_src, dinv, gcn1_b, bn1_g, bn1_b, bn1_m, bn1_v, bufA, n, 96);

    // ---- GAT1: h[N,96] @ W[96,192], H=2, C=96 ----
    k_gemm<<<nblk((long long)n * 192, B), B, 0, stream>>>(bufA, gat1_W, bufB, n, 96, 192);
    k_gat_logits<<<nblk(n * 2, B), B, 0, stream>>>(bufB, gat1_as, gat1_ad, alS, alD, n, 2, 96);
    k_gat_vh<<<nblk(n * 2, B), B, 0, stream>>>(row_ptr, csr_src, alS, alD, eex, selfw, invden, n, 2);
    k_gat_gather2<<<nblk((long long)n * 96, B), B, 0, stream>>>(
        bufB, row_ptr, csr_src, eex, selfw, invden, gat1_b, bufA, n, 96, 1);

    // ---- GCN2: h[N,96] @ W[96,96] -> gather -> +b, BN2, relu ----
    k_gemm<<<nblk((long long)n * 96, B), B, 0, stream>>>(bufA, gcn2_W, bufB, n, 96, 96);
    k_gcn_gather_bn<<<nblk((long long)n * 96, B), B, 0, stream>>>(
        bufB, row_ptr, csr_src, dinv, gcn2_b, bn2_g, bn2_b, bn2_m, bn2_v, bufA, n, 96);

    // ---- GAT2: h[N,96] @ W[96,80], H=2, C=40 ----
    k_gemm<<<nblk((long long)n * 80, B), B, 0, stream>>>(bufA, gat2_W, bufB, n, 96, 80);
    k_gat_logits<<<nblk(n * 2, B), B, 0, stream>>>(bufB, gat2_as, gat2_ad, alS, alD, n, 2, 40);
    k_gat_vh<<<nblk(n * 2, B), B, 0, stream>>>(row_ptr, csr_src, alS, alD, eex, selfw, invden, n, 2);
    k_gat_gather2<<<nblk((long long)n * 40, B), B, 0, stream>>>(
        bufB, row_ptr, csr_src, eex, selfw, invden, gat2_b, bufA, n, 40, 0);

    // ---- log_softmax -> d_out ----
    k_logsoftmax40<<<nblk(n, B), B, 0, stream>>>(bufA, out, n);
}

// Round 3
// 891.229 us; speedup vs baseline: 2.4385x; 1.4209x over previous
//
#include <hip/hip_runtime.h>
#include <math.h>

#define NNODES 50000
#define NEG_SLOPE 0.2f
#define BN_EPS 1e-5f

static __device__ __forceinline__ float leaky(float x) {
    return x > 0.f ? x : NEG_SLOPE * x;
}

// ---------------- CSR build ----------------
__global__ void k_zero_deg(int* degi, int n) {
    int v = blockIdx.x * blockDim.x + threadIdx.x;
    if (v < n) degi[v] = 0;
}
__global__ void k_count(const int* __restrict__ dst, int* degi, int E) {
    int e = blockIdx.x * blockDim.x + threadIdx.x;
    if (e < E) atomicAdd(&degi[dst[e]], 1);
}
__global__ void k_dinv(const int* __restrict__ degi, float* dinv, int n) {
    int v = blockIdx.x * blockDim.x + threadIdx.x;
    if (v < n) dinv[v] = rsqrtf((float)(degi[v] + 1));  // +1 self-loop
}
// single-block scan: row_ptr[v+1] = inclusive sum, cursor[v] = exclusive
__global__ void k_scan(const int* __restrict__ degi, int* __restrict__ row_ptr,
                       int* __restrict__ cursor, int n) {
    __shared__ int sdata[1024];
    __shared__ int carry;
    if (threadIdx.x == 0) { carry = 0; row_ptr[0] = 0; }
    __syncthreads();
    for (int base = 0; base < n; base += 1024) {
        int i = base + (int)threadIdx.x;
        int v = (i < n) ? degi[i] : 0;
        sdata[threadIdx.x] = v;
        __syncthreads();
        for (int off = 1; off < 1024; off <<= 1) {
            int t = (threadIdx.x >= (unsigned)off) ? sdata[threadIdx.x - off] : 0;
            __syncthreads();
            sdata[threadIdx.x] += t;
            __syncthreads();
        }
        int incl = sdata[threadIdx.x] + carry;
        if (i < n) {
            row_ptr[i + 1] = incl;
            cursor[i] = incl - v;
        }
        __syncthreads();
        if (threadIdx.x == 1023) carry = incl;
        __syncthreads();
    }
}
__global__ void k_fill(const int* __restrict__ src, const int* __restrict__ dst,
                       int* cursor, int* __restrict__ csr_src, int E) {
    int e = blockIdx.x * blockDim.x + threadIdx.x;
    if (e >= E) return;
    int pos = atomicAdd(&cursor[dst[e]], 1);
    csr_src[pos] = src[e];
}

// ---------------- tiled GEMM  C[n,Ko] = A[n,Ki] @ W[Ki,Ko] ----------------
// block: 64 rows x full Ko (Ko <= 32*TN). BK=16. 256 threads.
// thread (tx,ty): tx=col-group (32), ty=row-group (8). Register tile 8 x TN.
template<int TN>
__launch_bounds__(256)
__global__ void k_gemm_tile(const float* __restrict__ A, const float* __restrict__ W,
                            float* __restrict__ C, int n, int Ki, int Ko) {
    constexpr int KOP = 32 * TN;
    __shared__ float a_s[16][64];
    __shared__ float w_s[16][KOP];
    const int t = threadIdx.x;
    const int tx = t & 31, ty = t >> 5;
    const int row0 = blockIdx.x * 64;
    const int lrow = t & 63, lkq = t >> 6;  // A loader: row, kk-quad

    float acc[8][TN];
#pragma unroll
    for (int i = 0; i < 8; ++i)
#pragma unroll
        for (int j = 0; j < TN; ++j) acc[i][j] = 0.f;

    for (int k0 = 0; k0 < Ki; k0 += 16) {
        // stage A[row0:row0+64][k0:k0+16] transposed -> a_s[kk][row]
        {
            int r = row0 + lrow;
            float4 av = make_float4(0.f, 0.f, 0.f, 0.f);
            if (r < n) av = *(const float4*)&A[(long long)r * Ki + k0 + lkq * 4];
            a_s[lkq * 4 + 0][lrow] = av.x;
            a_s[lkq * 4 + 1][lrow] = av.y;
            a_s[lkq * 4 + 2][lrow] = av.z;
            a_s[lkq * 4 + 3][lrow] = av.w;
        }
        // stage W[k0:k0+16][0:Ko] (padded to KOP with zeros)
        for (int base = 0; base < 16 * KOP; base += 256) {
            int idx = base + t;
            int kk = idx / KOP, c = idx % KOP;
            w_s[kk][c] = (c < Ko) ? W[(k0 + kk) * Ko + c] : 0.f;
        }
        __syncthreads();
#pragma unroll 4
        for (int kk = 0; kk < 16; ++kk) {
            float a_r[8];
            *(float4*)&a_r[0] = *(const float4*)&a_s[kk][ty * 8];
            *(float4*)&a_r[4] = *(const float4*)&a_s[kk][ty * 8 + 4];
            float w_r[TN];
#pragma unroll
            for (int j = 0; j < TN; ++j) w_r[j] = w_s[kk][tx * TN + j];
#pragma unroll
            for (int i = 0; i < 8; ++i)
#pragma unroll
                for (int j = 0; j < TN; ++j)
                    acc[i][j] = fmaf(a_r[i], w_r[j], acc[i][j]);
        }
        __syncthreads();
    }
#pragma unroll
    for (int i = 0; i < 8; ++i) {
        int r = row0 + ty * 8 + i;
        if (r >= n) continue;
#pragma unroll
        for (int j = 0; j < TN; ++j) {
            int c = tx * TN + j;
            if (c < Ko) C[(long long)r * Ko + c] = acc[i][j];
        }
    }
}

// ---------------- GCN gather + bias + BN + relu ----------------
__global__ void k_gcn_gather_bn(const float* __restrict__ hin, const int* __restrict__ row_ptr,
                                const int* __restrict__ csr_src, const float* __restrict__ dinv,
                                const float* __restrict__ bias, const float* __restrict__ g,
                                const float* __restrict__ b, const float* __restrict__ m,
                                const float* __restrict__ vv,
                                float* __restrict__ out, int n, int C) {
    int t = blockIdx.x * blockDim.x + threadIdx.x;
    if (t >= n * C) return;
    int v = t / C, c = t % C;
    int beg = row_ptr[v], end = row_ptr[v + 1];
    float acc = dinv[v] * hin[t];
    for (int p = beg; p < end; ++p) {
        int s = csr_src[p];
        acc += dinv[s] * hin[s * C + c];
    }
    float x = acc * dinv[v] + bias[c];
    x = (x - m[c]) * rsqrtf(vv[c] + BN_EPS) * g[c] + b[c];
    out[t] = fmaxf(x, 0.f);
}

// ---------------- GAT ----------------
__global__ void k_gat_logits(const float* __restrict__ h, const float* __restrict__ as,
                             const float* __restrict__ ad, float* __restrict__ alS,
                             float* __restrict__ alD, int n, int H, int C) {
    int t = blockIdx.x * blockDim.x + threadIdx.x;
    if (t >= n * H) return;
    int hh = t % H;
    const float* row = h + (long long)t * C;  // layout [N, H, C]
    float s1 = 0.f, s2 = 0.f;
    for (int c = 0; c < C; ++c) {
        float x = row[c];
        s1 += x * as[hh * C + c];
        s2 += x * ad[hh * C + c];
    }
    alS[t] = s1; alD[t] = s2;
}
__global__ void k_gat_vh(const int* __restrict__ row_ptr, const int* __restrict__ csr_src,
                         const float* __restrict__ alS, const float* __restrict__ alD,
                         float* __restrict__ eex, float* __restrict__ selfw,
                         float* __restrict__ invden, int n, int H) {
    int t = blockIdx.x * blockDim.x + threadIdx.x;
    if (t >= n * H) return;
    int v = t / H, h = t % H;
    int beg = row_ptr[v], end = row_ptr[v + 1];
    float ad = alD[t];
    float l_self = leaky(alS[t] + ad);
    float mx = l_self;
    for (int p = beg; p < end; ++p) {
        int s = csr_src[p];
        mx = fmaxf(mx, leaky(alS[s * H + h] + ad));
    }
    float exs = expf(l_self - mx);
    float den = exs;
    for (int p = beg; p < end; ++p) {
        int s = csr_src[p];
        float ex = expf(leaky(alS[s * H + h] + ad) - mx);
        eex[p * H + h] = ex;
        den += ex;
    }
    selfw[t] = exs;
    invden[t] = 1.f / den;
}
__global__ void k_gat_gather2(const float* __restrict__ hin, const int* __restrict__ row_ptr,
                              const int* __restrict__ csr_src, const float* __restrict__ eex,
                              const float* __restrict__ selfw, const float* __restrict__ invden,
                              const float* __restrict__ bias, float* __restrict__ out,
                              int n, int C, int do_relu) {
    int t = blockIdx.x * blockDim.x + threadIdx.x;
    if (t >= n * C) return;
    int v = t / C, c = t % C;
    int beg = row_ptr[v], end = row_ptr[v + 1];
    int HC = 2 * C;
    float a0 = selfw[v * 2]     * hin[(long long)v * HC + c];
    float a1 = selfw[v * 2 + 1] * hin[(long long)v * HC + C + c];
    for (int p = beg; p < end; ++p) {
        int s = csr_src[p];
        const float* hr = hin + (long long)s * HC;
        a0 += eex[p * 2]     * hr[c];
        a1 += eex[p * 2 + 1] * hr[C + c];
    }
    float x = 0.5f * (a0 * invden[v * 2] + a1 * invden[v * 2 + 1]) + bias[c];
    out[t] = do_relu ? fmaxf(x, 0.f) : x;
}

__global__ void k_logsoftmax40(const float* __restrict__ in, float* __restrict__ out, int n) {
    int v = blockIdx.x * blockDim.x + threadIdx.x;
    if (v >= n) return;
    float vals[40];
    float mx = -INFINITY;
#pragma unroll
    for (int c = 0; c < 40; ++c) {
        float x = in[v * 40 + c];
        vals[c] = x;
        mx = fmaxf(mx, x);
    }
    float s = 0.f;
#pragma unroll
    for (int c = 0; c < 40; ++c) s += expf(vals[c] - mx);
    float ls = logf(s);
#pragma unroll
    for (int c = 0; c < 40; ++c) out[v * 40 + c] = vals[c] - mx - ls;
}

static inline int nblk(long long n, int b) { return (int)((n + b - 1) / b); }

extern "C" void kernel_launch(void* const* d_in, const int* in_sizes, int n_in,
                              void* d_out, int out_size, void* d_ws, size_t ws_size,
                              hipStream_t stream) {
    const float* x       = (const float*)d_in[0];
    const int*   ei      = (const int*)d_in[1];
    const float* gcn1_W  = (const float*)d_in[2];
    const float* gcn1_b  = (const float*)d_in[3];
    const float* bn1_g   = (const float*)d_in[4];
    const float* bn1_b   = (const float*)d_in[5];
    const float* bn1_m   = (const float*)d_in[6];
    const float* bn1_v   = (const float*)d_in[7];
    const float* gat1_W  = (const float*)d_in[8];
    const float* gat1_as = (const float*)d_in[9];
    const float* gat1_ad = (const float*)d_in[10];
    const float* gat1_b  = (const float*)d_in[11];
    const float* gcn2_W  = (const float*)d_in[12];
    const float* gcn2_b  = (const float*)d_in[13];
    const float* bn2_g   = (const float*)d_in[14];
    const float* bn2_b   = (const float*)d_in[15];
    const float* bn2_m   = (const float*)d_in[16];
    const float* bn2_v   = (const float*)d_in[17];
    const float* gat2_W  = (const float*)d_in[18];
    const float* gat2_as = (const float*)d_in[19];
    const float* gat2_ad = (const float*)d_in[20];
    const float* gat2_b  = (const float*)d_in[21];

    const int n = NNODES;
    const int E = in_sizes[1] / 2;
    const int* src = ei;
    const int* dst = ei + E;

    // ---- workspace carve (bytes) ----
    char* p = (char*)d_ws;
    float* dinv    = (float*)p; p += 50048 * 4;
    int*   degi    = (int*)p;   p += 50048 * 4;
    int*   row_ptr = (int*)p;   p += 50052 * 4;
    int*   cursor  = (int*)p;   p += 50048 * 4;
    int*   csr_src = (int*)p;   p += 800000 * 4;
    float* bufA    = (float*)p; p += 9600000 * 4;
    float* bufB    = (float*)p; p += 9600000 * 4;
    float* alS     = (float*)p; p += 100096 * 4;
    float* alD     = (float*)p; p += 100096 * 4;
    float* selfw   = (float*)p; p += 100096 * 4;
    float* invden  = (float*)p; p += 100096 * 4;
    float* eex     = (float*)p; p += 1600000 * 4;

    const int B = 256;
    const int GB = nblk(n, 64);  // GEMM row-tile blocks
    float* out = (float*)d_out;

    // ---- CSR build (shared by all 4 graph layers) ----
    k_zero_deg<<<nblk(n, B), B, 0, stream>>>(degi, n);
    k_count<<<nblk(E, B), B, 0, stream>>>(dst, degi, E);
    k_dinv<<<nblk(n, B), B, 0, stream>>>(degi, dinv, n);
    k_scan<<<1, 1024, 0, stream>>>(degi, row_ptr, cursor, n);
    k_fill<<<nblk(E, B), B, 0, stream>>>(src, dst, cursor, csr_src, E);

    // ---- GCN1: x[N,128] @ W[128,96] -> gather -> +b, BN1, relu ----
    k_gemm_tile<3><<<GB, 256, 0, stream>>>(x, gcn1_W, bufB, n, 128, 96);
    k_gcn_gather_bn<<<nblk((long long)n * 96, B), B, 0, stream>>>(
        bufB, row_ptr, csr_src, dinv, gcn1_b, bn1_g, bn1_b, bn1_m, bn1_v, bufA, n, 96);

    // ---- GAT1: h[N,96] @ W[96,192], H=2, C=96 ----
    k_gemm_tile<6><<<GB, 256, 0, stream>>>(bufA, gat1_W, bufB, n, 96, 192);
    k_gat_logits<<<nblk(n * 2, B), B, 0, stream>>>(bufB, gat1_as, gat1_ad, alS, alD, n, 2, 96);
    k_gat_vh<<<nblk(n * 2, B), B, 0, stream>>>(row_ptr, csr_src, alS, alD, eex, selfw, invden, n, 2);
    k_gat_gather2<<<nblk((long long)n * 96, B), B, 0, stream>>>(
        bufB, row_ptr, csr_src, eex, selfw, invden, gat1_b, bufA, n, 96, 1);

    // ---- GCN2: h[N,96] @ W[96,96] -> gather -> +b, BN2, relu ----
    k_gemm_tile<3><<<GB, 256, 0, stream>>>(bufA, gcn2_W, bufB, n, 96, 96);
    k_gcn_gather_bn<<<nblk((long long)n * 96, B), B, 0, stream>>>(
        bufB, row_ptr, csr_src, dinv, gcn2_b, bn2_g, bn2_b, bn2_m, bn2_v, bufA, n, 96);

    // ---- GAT2: h[N,96] @ W[96,80], H=2, C=40 ----
    k_gemm_tile<3><<<GB, 256, 0, stream>>>(bufA, gat2_W, bufB, n, 96, 80);
    k_gat_logits<<<nblk(n * 2, B), B, 0, stream>>>(bufB, gat2_as, gat2_ad, alS, alD, n, 2, 40);
    k_gat_vh<<<nblk(n * 2, B), B, 0, stream>>>(row_ptr, csr_src, alS, alD, eex, selfw, invden, n, 2);
    k_gat_gather2<<<nblk((long long)n * 40, B), B, 0, stream>>>(
        bufB, row_ptr, csr_src, eex, selfw, invden, gat2_b, bufA, n, 40, 0);

    // ---- log_softmax -> d_out ----
    k_logsoftmax40<<<nblk(n, B), B, 0, stream>>>(bufA, out, n);
}

// Round 4
// 737.907 us; speedup vs baseline: 2.9452x; 1.2078x over previous
//
#include <hip/hip_runtime.h>
#include <math.h>

#define NNODES 50000
#define NEG_SLOPE 0.2f
#define BN_EPS 1e-5f

static __device__ __forceinline__ float leaky(float x) {
    return x > 0.f ? x : NEG_SLOPE * x;
}
static __device__ __forceinline__ float4 f4s(float s, float4 a) {
    return make_float4(s * a.x, s * a.y, s * a.z, s * a.w);
}
static __device__ __forceinline__ float4 f4fma(float s, float4 a, float4 acc) {
    return make_float4(fmaf(s, a.x, acc.x), fmaf(s, a.y, acc.y),
                       fmaf(s, a.z, acc.z), fmaf(s, a.w, acc.w));
}

// ---------------- CSR build ----------------
__global__ void k_zero_deg(int* degi, int n) {
    int v = blockIdx.x * blockDim.x + threadIdx.x;
    if (v < n) degi[v] = 0;
}
__global__ void k_count(const int* __restrict__ dst, int* degi, int E) {
    int e = blockIdx.x * blockDim.x + threadIdx.x;
    if (e < E) atomicAdd(&degi[dst[e]], 1);
}
__global__ void k_dinv(const int* __restrict__ degi, float* dinv, int n) {
    int v = blockIdx.x * blockDim.x + threadIdx.x;
    if (v < n) dinv[v] = rsqrtf((float)(degi[v] + 1));  // +1 self-loop
}
__global__ void k_scan(const int* __restrict__ degi, int* __restrict__ row_ptr,
                       int* __restrict__ cursor, int n) {
    __shared__ int sdata[1024];
    __shared__ int carry;
    if (threadIdx.x == 0) { carry = 0; row_ptr[0] = 0; }
    __syncthreads();
    for (int base = 0; base < n; base += 1024) {
        int i = base + (int)threadIdx.x;
        int v = (i < n) ? degi[i] : 0;
        sdata[threadIdx.x] = v;
        __syncthreads();
        for (int off = 1; off < 1024; off <<= 1) {
            int t = (threadIdx.x >= (unsigned)off) ? sdata[threadIdx.x - off] : 0;
            __syncthreads();
            sdata[threadIdx.x] += t;
            __syncthreads();
        }
        int incl = sdata[threadIdx.x] + carry;
        if (i < n) {
            row_ptr[i + 1] = incl;
            cursor[i] = incl - v;
        }
        __syncthreads();
        if (threadIdx.x == 1023) carry = incl;
        __syncthreads();
    }
}
__global__ void k_fill(const int* __restrict__ src, const int* __restrict__ dst,
                       int* cursor, int* __restrict__ csr_src, int E) {
    int e = blockIdx.x * blockDim.x + threadIdx.x;
    if (e >= E) return;
    int pos = atomicAdd(&cursor[dst[e]], 1);
    csr_src[pos] = src[e];
}

// ---------------- tiled GEMM  C[n,Ko] = A[n,Ki] @ W[Ki,Ko] ----------------
template<int TN>
__launch_bounds__(256)
__global__ void k_gemm_tile(const float* __restrict__ A, const float* __restrict__ W,
                            float* __restrict__ C, int n, int Ki, int Ko) {
    constexpr int KOP = 32 * TN;
    __shared__ float a_s[16][64];
    __shared__ float w_s[16][KOP];
    const int t = threadIdx.x;
    const int tx = t & 31, ty = t >> 5;
    const int row0 = blockIdx.x * 64;
    const int lrow = t & 63, lkq = t >> 6;

    float acc[8][TN];
#pragma unroll
    for (int i = 0; i < 8; ++i)
#pragma unroll
        for (int j = 0; j < TN; ++j) acc[i][j] = 0.f;

    for (int k0 = 0; k0 < Ki; k0 += 16) {
        {
            int r = row0 + lrow;
            float4 av = make_float4(0.f, 0.f, 0.f, 0.f);
            if (r < n) av = *(const float4*)&A[(long long)r * Ki + k0 + lkq * 4];
            a_s[lkq * 4 + 0][lrow] = av.x;
            a_s[lkq * 4 + 1][lrow] = av.y;
            a_s[lkq * 4 + 2][lrow] = av.z;
            a_s[lkq * 4 + 3][lrow] = av.w;
        }
        for (int base = 0; base < 16 * KOP; base += 256) {
            int idx = base + t;
            int kk = idx / KOP, c = idx % KOP;
            w_s[kk][c] = (c < Ko) ? W[(k0 + kk) * Ko + c] : 0.f;
        }
        __syncthreads();
#pragma unroll 4
        for (int kk = 0; kk < 16; ++kk) {
            float a_r[8];
            *(float4*)&a_r[0] = *(const float4*)&a_s[kk][ty * 8];
            *(float4*)&a_r[4] = *(const float4*)&a_s[kk][ty * 8 + 4];
            float w_r[TN];
#pragma unroll
            for (int j = 0; j < TN; ++j) w_r[j] = w_s[kk][tx * TN + j];
#pragma unroll
            for (int i = 0; i < 8; ++i)
#pragma unroll
                for (int j = 0; j < TN; ++j)
                    acc[i][j] = fmaf(a_r[i], w_r[j], acc[i][j]);
        }
        __syncthreads();
    }
#pragma unroll
    for (int i = 0; i < 8; ++i) {
        int r = row0 + ty * 8 + i;
        if (r >= n) continue;
#pragma unroll
        for (int j = 0; j < TN; ++j) {
            int c = tx * TN + j;
            if (c < Ko) C[(long long)r * Ko + c] = acc[i][j];
        }
    }
}

// ---------------- GCN gather (float4) + bias + BN + relu ----------------
// thread = v*Q + cq, Q = C/4
__global__ void k_gcn_gather_bn4(const float4* __restrict__ hin4, const int* __restrict__ row_ptr,
                                 const int* __restrict__ csr_src, const float* __restrict__ dinv,
                                 const float* __restrict__ bias, const float* __restrict__ g,
                                 const float* __restrict__ b, const float* __restrict__ m,
                                 const float* __restrict__ vv,
                                 float4* __restrict__ out4, int n, int Q) {
    int t = blockIdx.x * blockDim.x + threadIdx.x;
    if (t >= n * Q) return;
    int v = t / Q, cq = t % Q;
    int beg = row_ptr[v], end = row_ptr[v + 1];
    float dv = dinv[v];
    float4 acc = f4s(dv, hin4[(long long)v * Q + cq]);
    for (int p = beg; p < end; ++p) {
        int s = csr_src[p];
        acc = f4fma(dinv[s], hin4[(long long)s * Q + cq], acc);
    }
    float4 bi = ((const float4*)bias)[cq];
    float4 gg = ((const float4*)g)[cq];
    float4 bb = ((const float4*)b)[cq];
    float4 mm = ((const float4*)m)[cq];
    float4 vvv = ((const float4*)vv)[cq];
    float4 x;
    x.x = fmaxf((fmaf(acc.x, dv, bi.x) - mm.x) * rsqrtf(vvv.x + BN_EPS) * gg.x + bb.x, 0.f);
    x.y = fmaxf((fmaf(acc.y, dv, bi.y) - mm.y) * rsqrtf(vvv.y + BN_EPS) * gg.y + bb.y, 0.f);
    x.z = fmaxf((fmaf(acc.z, dv, bi.z) - mm.z) * rsqrtf(vvv.z + BN_EPS) * gg.z + bb.z, 0.f);
    x.w = fmaxf((fmaf(acc.w, dv, bi.w) - mm.w) * rsqrtf(vvv.w + BN_EPS) * gg.w + bb.w, 0.f);
    out4[(long long)v * Q + cq] = x;
}

// ---------------- GAT ----------------
__global__ void k_gat_logits(const float* __restrict__ h, const float* __restrict__ as,
                             const float* __restrict__ ad, float* __restrict__ alS,
                             float* __restrict__ alD, int n, int H, int C) {
    int t = blockIdx.x * blockDim.x + threadIdx.x;
    if (t >= n * H) return;
    int hh = t % H;
    const float* row = h + (long long)t * C;  // layout [N, H, C]
    float s1 = 0.f, s2 = 0.f;
    for (int c = 0; c < C; ++c) {
        float x = row[c];
        s1 += x * as[hh * C + c];
        s2 += x * ad[hh * C + c];
    }
    alS[t] = s1; alD[t] = s2;
}
// two-pass softmax; pass1 stashes leaky logits in eex, pass2 rereads sequentially
__global__ void k_gat_vh(const int* __restrict__ row_ptr, const int* __restrict__ csr_src,
                         const float* __restrict__ alS, const float* __restrict__ alD,
                         float* __restrict__ eex, float* __restrict__ selfw,
                         float* __restrict__ invden, int n, int H) {
    int t = blockIdx.x * blockDim.x + threadIdx.x;
    if (t >= n * H) return;
    int v = t / H, h = t % H;
    int beg = row_ptr[v], end = row_ptr[v + 1];
    float ad = alD[t];
    float l_self = leaky(alS[t] + ad);
    float mx = l_self;
    for (int p = beg; p < end; ++p) {
        int s = csr_src[p];
        float l = leaky(alS[s * H + h] + ad);
        eex[p * H + h] = l;
        mx = fmaxf(mx, l);
    }
    float exs = expf(l_self - mx);
    float den = exs;
    for (int p = beg; p < end; ++p) {
        float ex = expf(eex[p * H + h] - mx);
        eex[p * H + h] = ex;
        den += ex;
    }
    selfw[t] = exs;
    invden[t] = 1.f / den;
}
// H=2 gather (float4, both heads per thread) + head-mean + bias (+relu)
// thread = v*Q + cq, Q = C/4; hin rows have 2*Q quads [head0 | head1]
__global__ void k_gat_gather2_4(const float4* __restrict__ hin4, const int* __restrict__ row_ptr,
                                const int* __restrict__ csr_src, const float2* __restrict__ eex2,
                                const float2* __restrict__ selfw2, const float2* __restrict__ invden2,
                                const float* __restrict__ bias, float4* __restrict__ out4,
                                int n, int Q, int do_relu) {
    int t = blockIdx.x * blockDim.x + threadIdx.x;
    if (t >= n * Q) return;
    int v = t / Q, cq = t % Q;
    int QH = 2 * Q;
    int beg = row_ptr[v], end = row_ptr[v + 1];
    const float4* hv = hin4 + (long long)v * QH;
    float2 sw = selfw2[v];
    float4 A0 = f4s(sw.x, hv[cq]);
    float4 A1 = f4s(sw.y, hv[Q + cq]);
    for (int p = beg; p < end; ++p) {
        int s = csr_src[p];
        float2 w = eex2[p];
        const float4* hs = hin4 + (long long)s * QH;
        A0 = f4fma(w.x, hs[cq], A0);
        A1 = f4fma(w.y, hs[Q + cq], A1);
    }
    float2 idn = invden2[v];
    float4 bi = ((const float4*)bias)[cq];
    float4 x;
    x.x = fmaf(0.5f, fmaf(A0.x, idn.x, A1.x * idn.y), bi.x);
    x.y = fmaf(0.5f, fmaf(A0.y, idn.x, A1.y * idn.y), bi.y);
    x.z = fmaf(0.5f, fmaf(A0.z, idn.x, A1.z * idn.y), bi.z);
    x.w = fmaf(0.5f, fmaf(A0.w, idn.x, A1.w * idn.y), bi.w);
    if (do_relu) {
        x.x = fmaxf(x.x, 0.f); x.y = fmaxf(x.y, 0.f);
        x.z = fmaxf(x.z, 0.f); x.w = fmaxf(x.w, 0.f);
    }
    out4[(long long)v * Q + cq] = x;
}

__global__ void k_logsoftmax40(const float* __restrict__ in, float* __restrict__ out, int n) {
    int v = blockIdx.x * blockDim.x + threadIdx.x;
    if (v >= n) return;
    float vals[40];
    float mx = -INFINITY;
#pragma unroll
    for (int c = 0; c < 40; ++c) {
        float x = in[v * 40 + c];
        vals[c] = x;
        mx = fmaxf(mx, x);
    }
    float s = 0.f;
#pragma unroll
    for (int c = 0; c < 40; ++c) s += expf(vals[c] - mx);
    float ls = logf(s);
#pragma unroll
    for (int c = 0; c < 40; ++c) out[v * 40 + c] = vals[c] - mx - ls;
}

static inline int nblk(long long n, int b) { return (int)((n + b - 1) / b); }

extern "C" void kernel_launch(void* const* d_in, const int* in_sizes, int n_in,
                              void* d_out, int out_size, void* d_ws, size_t ws_size,
                              hipStream_t stream) {
    const float* x       = (const float*)d_in[0];
    const int*   ei      = (const int*)d_in[1];
    const float* gcn1_W  = (const float*)d_in[2];
    const float* gcn1_b  = (const float*)d_in[3];
    const float* bn1_g   = (const float*)d_in[4];
    const float* bn1_b   = (const float*)d_in[5];
    const float* bn1_m   = (const float*)d_in[6];
    const float* bn1_v   = (const float*)d_in[7];
    const float* gat1_W  = (const float*)d_in[8];
    const float* gat1_as = (const float*)d_in[9];
    const float* gat1_ad = (const float*)d_in[10];
    const float* gat1_b  = (const float*)d_in[11];
    const float* gcn2_W  = (const float*)d_in[12];
    const float* gcn2_b  = (const float*)d_in[13];
    const float* bn2_g   = (const float*)d_in[14];
    const float* bn2_b   = (const float*)d_in[15];
    const float* bn2_m   = (const float*)d_in[16];
    const float* bn2_v   = (const float*)d_in[17];
    const float* gat2_W  = (const float*)d_in[18];
    const float* gat2_as = (const float*)d_in[19];
    const float* gat2_ad = (const float*)d_in[20];
    const float* gat2_b  = (const float*)d_in[21];

    const int n = NNODES;
    const int E = in_sizes[1] / 2;
    const int* src = ei;
    const int* dst = ei + E;

    // ---- workspace carve (16B-aligned chunks) ----
    char* p = (char*)d_ws;
    float* dinv    = (float*)p; p += 50048 * 4;
    int*   degi    = (int*)p;   p += 50048 * 4;
    int*   row_ptr = (int*)p;   p += 50052 * 4;
    int*   cursor  = (int*)p;   p += 50048 * 4;
    int*   csr_src = (int*)p;   p += 800000 * 4;
    float* bufA    = (float*)p; p += 9600000 * 4;
    float* bufB    = (float*)p; p += 9600000 * 4;
    float* alS     = (float*)p; p += 100096 * 4;
    float* alD     = (float*)p; p += 100096 * 4;
    float* selfw   = (float*)p; p += 100096 * 4;
    float* invden  = (float*)p; p += 100096 * 4;
    float* eex     = (float*)p; p += 1600000 * 4;

    const int B = 256;
    const int GB = nblk(n, 64);
    float* out = (float*)d_out;

    // ---- CSR build (shared by all 4 graph layers) ----
    k_zero_deg<<<nblk(n, B), B, 0, stream>>>(degi, n);
    k_count<<<nblk(E, B), B, 0, stream>>>(dst, degi, E);
    k_dinv<<<nblk(n, B), B, 0, stream>>>(degi, dinv, n);
    k_scan<<<1, 1024, 0, stream>>>(degi, row_ptr, cursor, n);
    k_fill<<<nblk(E, B), B, 0, stream>>>(src, dst, cursor, csr_src, E);

    // ---- GCN1: x[N,128] @ W[128,96] -> gather -> +b, BN1, relu ----
    k_gemm_tile<3><<<GB, 256, 0, stream>>>(x, gcn1_W, bufB, n, 128, 96);
    k_gcn_gather_bn4<<<nblk((long long)n * 24, B), B, 0, stream>>>(
        (const float4*)bufB, row_ptr, csr_src, dinv, gcn1_b, bn1_g, bn1_b, bn1_m, bn1_v,
        (float4*)bufA, n, 24);

    // ---- GAT1: h[N,96] @ W[96,192], H=2, C=96 ----
    k_gemm_tile<6><<<GB, 256, 0, stream>>>(bufA, gat1_W, bufB, n, 96, 192);
    k_gat_logits<<<nblk(n * 2, B), B, 0, stream>>>(bufB, gat1_as, gat1_ad, alS, alD, n, 2, 96);
    k_gat_vh<<<nblk(n * 2, B), B, 0, stream>>>(row_ptr, csr_src, alS, alD, eex, selfw, invden, n, 2);
    k_gat_gather2_4<<<nblk((long long)n * 24, B), B, 0, stream>>>(
        (const float4*)bufB, row_ptr, csr_src, (const float2*)eex, (const float2*)selfw,
        (const float2*)invden, gat1_b, (float4*)bufA, n, 24, 1);

    // ---- GCN2: h[N,96] @ W[96,96] -> gather -> +b, BN2, relu ----
    k_gemm_tile<3><<<GB, 256, 0, stream>>>(bufA, gcn2_W, bufB, n, 96, 96);
    k_gcn_gather_bn4<<<nblk((long long)n * 24, B), B, 0, stream>>>(
        (const float4*)bufB, row_ptr, csr_src, dinv, gcn2_b, bn2_g, bn2_b, bn2_m, bn2_v,
        (float4*)bufA, n, 24);

    // ---- GAT2: h[N,96] @ W[96,80], H=2, C=40 ----
    k_gemm_tile<3><<<GB, 256, 0, stream>>>(bufA, gat2_W, bufB, n, 96, 80);
    k_gat_logits<<<nblk(n * 2, B), B, 0, stream>>>(bufB, gat2_as, gat2_ad, alS, alD, n, 2, 40);
    k_gat_vh<<<nblk(n * 2, B), B, 0, stream>>>(row_ptr, csr_src, alS, alD, eex, selfw, invden, n, 2);
    k_gat_gather2_4<<<nblk((long long)n * 10, B), B, 0, stream>>>(
        (const float4*)bufB, row_ptr, csr_src, (const float2*)eex, (const float2*)selfw,
        (const float2*)invden, gat2_b, (float4*)bufA, n, 10, 0);

    // ---- log_softmax -> d_out ----
    k_logsoftmax40<<<nblk(n, B), B, 0, stream>>>(bufA, out, n);
}

// Round 5
// 584.159 us; speedup vs baseline: 3.7204x; 1.2632x over previous
//
#include <hip/hip_runtime.h>
#include <math.h>

#define NNODES 50000
#define NEG_SLOPE 0.2f
#define BN_EPS 1e-5f

static __device__ __forceinline__ float leaky(float x) {
    return x > 0.f ? x : NEG_SLOPE * x;
}
// f32 -> bf16 (RNE) and back
static __device__ __forceinline__ unsigned short f2bf(float x) {
    unsigned u = __float_as_uint(x);
    u += 0x7FFFu + ((u >> 16) & 1u);
    return (unsigned short)(u >> 16);
}
// unpack 8 bf16 (uint4) -> 8 f32
static __device__ __forceinline__ void unpack8(uint4 u, float* v) {
    v[0] = __uint_as_float(u.x << 16);
    v[1] = __uint_as_float(u.x & 0xFFFF0000u);
    v[2] = __uint_as_float(u.y << 16);
    v[3] = __uint_as_float(u.y & 0xFFFF0000u);
    v[4] = __uint_as_float(u.z << 16);
    v[5] = __uint_as_float(u.z & 0xFFFF0000u);
    v[6] = __uint_as_float(u.w << 16);
    v[7] = __uint_as_float(u.w & 0xFFFF0000u);
}
static __device__ __forceinline__ void acc8(uint4 u, float w, float* a) {
    float v[8]; unpack8(u, v);
#pragma unroll
    for (int j = 0; j < 8; ++j) a[j] = fmaf(w, v[j], a[j]);
}

// ---------------- CSR build ----------------
__global__ void k_zero_deg(int* degi, int n) {
    int v = blockIdx.x * blockDim.x + threadIdx.x;
    if (v < n) degi[v] = 0;
}
__global__ void k_count(const int* __restrict__ dst, int* degi, int E) {
    int e = blockIdx.x * blockDim.x + threadIdx.x;
    if (e < E) atomicAdd(&degi[dst[e]], 1);
}
__global__ void k_dinv(const int* __restrict__ degi, float* dinv, int n) {
    int v = blockIdx.x * blockDim.x + threadIdx.x;
    if (v < n) dinv[v] = rsqrtf((float)(degi[v] + 1));  // +1 self-loop
}
__global__ void k_scan(const int* __restrict__ degi, int* __restrict__ row_ptr,
                       int* __restrict__ cursor, int n) {
    __shared__ int sdata[1024];
    __shared__ int carry;
    if (threadIdx.x == 0) { carry = 0; row_ptr[0] = 0; }
    __syncthreads();
    for (int base = 0; base < n; base += 1024) {
        int i = base + (int)threadIdx.x;
        int v = (i < n) ? degi[i] : 0;
        sdata[threadIdx.x] = v;
        __syncthreads();
        for (int off = 1; off < 1024; off <<= 1) {
            int t = (threadIdx.x >= (unsigned)off) ? sdata[threadIdx.x - off] : 0;
            __syncthreads();
            sdata[threadIdx.x] += t;
            __syncthreads();
        }
        int incl = sdata[threadIdx.x] + carry;
        if (i < n) {
            row_ptr[i + 1] = incl;
            cursor[i] = incl - v;
        }
        __syncthreads();
        if (threadIdx.x == 1023) carry = incl;
        __syncthreads();
    }
}
__global__ void k_fill(const int* __restrict__ src, const int* __restrict__ dst,
                       int* cursor, int* __restrict__ csr_src, int E) {
    int e = blockIdx.x * blockDim.x + threadIdx.x;
    if (e >= E) return;
    int pos = atomicAdd(&cursor[dst[e]], 1);
    csr_src[pos] = src[e];
}

// ---------------- tiled GEMM, bf16 output ----------------
template<int TN>
__launch_bounds__(256)
__global__ void k_gemm_tile(const float* __restrict__ A, const float* __restrict__ W,
                            unsigned short* __restrict__ C, int n, int Ki, int Ko) {
    constexpr int KOP = 32 * TN;
    __shared__ float a_s[16][64];
    __shared__ float w_s[16][KOP];
    const int t = threadIdx.x;
    const int tx = t & 31, ty = t >> 5;
    const int row0 = blockIdx.x * 64;
    const int lrow = t & 63, lkq = t >> 6;

    float acc[8][TN];
#pragma unroll
    for (int i = 0; i < 8; ++i)
#pragma unroll
        for (int j = 0; j < TN; ++j) acc[i][j] = 0.f;

    for (int k0 = 0; k0 < Ki; k0 += 16) {
        {
            int r = row0 + lrow;
            float4 av = make_float4(0.f, 0.f, 0.f, 0.f);
            if (r < n) av = *(const float4*)&A[(long long)r * Ki + k0 + lkq * 4];
            a_s[lkq * 4 + 0][lrow] = av.x;
            a_s[lkq * 4 + 1][lrow] = av.y;
            a_s[lkq * 4 + 2][lrow] = av.z;
            a_s[lkq * 4 + 3][lrow] = av.w;
        }
        for (int base = 0; base < 16 * KOP; base += 256) {
            int idx = base + t;
            int kk = idx / KOP, c = idx % KOP;
            w_s[kk][c] = (c < Ko) ? W[(k0 + kk) * Ko + c] : 0.f;
        }
        __syncthreads();
#pragma unroll 4
        for (int kk = 0; kk < 16; ++kk) {
            float a_r[8];
            *(float4*)&a_r[0] = *(const float4*)&a_s[kk][ty * 8];
            *(float4*)&a_r[4] = *(const float4*)&a_s[kk][ty * 8 + 4];
            float w_r[TN];
#pragma unroll
            for (int j = 0; j < TN; ++j) w_r[j] = w_s[kk][tx * TN + j];
#pragma unroll
            for (int i = 0; i < 8; ++i)
#pragma unroll
                for (int j = 0; j < TN; ++j)
                    acc[i][j] = fmaf(a_r[i], w_r[j], acc[i][j]);
        }
        __syncthreads();
    }
#pragma unroll
    for (int i = 0; i < 8; ++i) {
        int r = row0 + ty * 8 + i;
        if (r >= n) continue;
#pragma unroll
        for (int j = 0; j < TN; ++j) {
            int c = tx * TN + j;
            if (c < Ko) C[(long long)r * Ko + c] = f2bf(acc[i][j]);
        }
    }
}

// ---------------- GCN gather (bf16 in, 8ch/thread) + bias + BN + relu ----------------
// thread = v*Q8 + q; h row = Q8 uint4 octets
__global__ void k_gcn_gather_bn8(const uint4* __restrict__ hb, const int* __restrict__ row_ptr,
                                 const int* __restrict__ csr_src, const float* __restrict__ dinv,
                                 const float* __restrict__ bias, const float* __restrict__ g,
                                 const float* __restrict__ b, const float* __restrict__ m,
                                 const float* __restrict__ vv,
                                 float4* __restrict__ out4, int n, int Q8) {
    int t = blockIdx.x * blockDim.x + threadIdx.x;
    if (t >= n * Q8) return;
    int v = t / Q8, q = t % Q8;
    int beg = row_ptr[v], end = row_ptr[v + 1];
    float dv = dinv[v];
    float a[8] = {0.f, 0.f, 0.f, 0.f, 0.f, 0.f, 0.f, 0.f};
    acc8(hb[(long long)v * Q8 + q], dv, a);
    for (int p = beg; p < end; ++p) {
        int s = csr_src[p];
        acc8(hb[(long long)s * Q8 + q], dinv[s], a);
    }
    int c0 = q * 8;
    float o[8];
#pragma unroll
    for (int j = 0; j < 8; ++j) {
        int c = c0 + j;
        float x = fmaf(a[j], dv, bias[c]);
        x = (x - m[c]) * rsqrtf(vv[c] + BN_EPS) * g[c] + b[c];
        o[j] = fmaxf(x, 0.f);
    }
    long long ob = (long long)v * (Q8 * 2) + q * 2;
    out4[ob]     = make_float4(o[0], o[1], o[2], o[3]);
    out4[ob + 1] = make_float4(o[4], o[5], o[6], o[7]);
}

// ---------------- GAT ----------------
// logits from bf16 h
__global__ void k_gat_logits8(const uint4* __restrict__ hb, const float* __restrict__ as,
                              const float* __restrict__ ad, float* __restrict__ alS,
                              float* __restrict__ alD, int n, int C) {
    int t = blockIdx.x * blockDim.x + threadIdx.x;
    if (t >= n * 2) return;
    int hh = t & 1;
    int C8 = C >> 3;
    const uint4* row = hb + (long long)t * C8;  // [N, 2, C8]
    float s1 = 0.f, s2 = 0.f;
    for (int q = 0; q < C8; ++q) {
        float v[8]; unpack8(row[q], v);
#pragma unroll
        for (int j = 0; j < 8; ++j) {
            int c = hh * C + q * 8 + j;
            s1 = fmaf(v[j], as[c], s1);
            s2 = fmaf(v[j], ad[c], s2);
        }
    }
    alS[t] = s1; alD[t] = s2;
}
// two-pass softmax; pass1 stashes leaky logits in eex, pass2 rereads sequentially
__global__ void k_gat_vh(const int* __restrict__ row_ptr, const int* __restrict__ csr_src,
                         const float* __restrict__ alS, const float* __restrict__ alD,
                         float* __restrict__ eex, float* __restrict__ selfw,
                         float* __restrict__ invden, int n, int H) {
    int t = blockIdx.x * blockDim.x + threadIdx.x;
    if (t >= n * H) return;
    int v = t / H, h = t % H;
    int beg = row_ptr[v], end = row_ptr[v + 1];
    float ad = alD[t];
    float l_self = leaky(alS[t] + ad);
    float mx = l_self;
    for (int p = beg; p < end; ++p) {
        int s = csr_src[p];
        float l = leaky(alS[s * H + h] + ad);
        eex[p * H + h] = l;
        mx = fmaxf(mx, l);
    }
    float exs = expf(l_self - mx);
    float den = exs;
    for (int p = beg; p < end; ++p) {
        float ex = expf(eex[p * H + h] - mx);
        eex[p * H + h] = ex;
        den += ex;
    }
    selfw[t] = exs;
    invden[t] = 1.f / den;
}
// H=2 gather (bf16 in, 8ch/thread both heads) + head-mean + bias (+relu)
__global__ void k_gat_gather2_8(const uint4* __restrict__ hb, const int* __restrict__ row_ptr,
                                const int* __restrict__ csr_src, const float2* __restrict__ eex2,
                                const float2* __restrict__ selfw2, const float2* __restrict__ invden2,
                                const float* __restrict__ bias, float4* __restrict__ out4,
                                int n, int Q8, int do_relu) {
    int t = blockIdx.x * blockDim.x + threadIdx.x;
    if (t >= n * Q8) return;
    int v = t / Q8, q = t % Q8;
    int rowOct = 2 * Q8;
    int beg = row_ptr[v], end = row_ptr[v + 1];
    float A0[8] = {0,0,0,0,0,0,0,0}, A1[8] = {0,0,0,0,0,0,0,0};
    {
        float2 sw = selfw2[v];
        const uint4* hv = hb + (long long)v * rowOct;
        acc8(hv[q], sw.x, A0);
        acc8(hv[Q8 + q], sw.y, A1);
    }
    for (int p = beg; p < end; ++p) {
        int s = csr_src[p];
        float2 w = eex2[p];
        const uint4* hs = hb + (long long)s * rowOct;
        acc8(hs[q], w.x, A0);
        acc8(hs[Q8 + q], w.y, A1);
    }
    float2 idn = invden2[v];
    int c0 = q * 8;
    float o[8];
#pragma unroll
    for (int j = 0; j < 8; ++j) {
        float x = fmaf(0.5f, fmaf(A0[j], idn.x, A1[j] * idn.y), bias[c0 + j]);
        o[j] = do_relu ? fmaxf(x, 0.f) : x;
    }
    long long ob = (long long)v * (Q8 * 2) + q * 2;
    out4[ob]     = make_float4(o[0], o[1], o[2], o[3]);
    out4[ob + 1] = make_float4(o[4], o[5], o[6], o[7]);
}

__global__ void k_logsoftmax40(const float* __restrict__ in, float* __restrict__ out, int n) {
    int v = blockIdx.x * blockDim.x + threadIdx.x;
    if (v >= n) return;
    float vals[40];
    float mx = -INFINITY;
#pragma unroll
    for (int c = 0; c < 40; ++c) {
        float x = in[v * 40 + c];
        vals[c] = x;
        mx = fmaxf(mx, x);
    }
    float s = 0.f;
#pragma unroll
    for (int c = 0; c < 40; ++c) s += expf(vals[c] - mx);
    float ls = logf(s);
#pragma unroll
    for (int c = 0; c < 40; ++c) out[v * 40 + c] = vals[c] - mx - ls;
}

static inline int nblk(long long n, int b) { return (int)((n + b - 1) / b); }

extern "C" void kernel_launch(void* const* d_in, const int* in_sizes, int n_in,
                              void* d_out, int out_size, void* d_ws, size_t ws_size,
                              hipStream_t stream) {
    const float* x       = (const float*)d_in[0];
    const int*   ei      = (const int*)d_in[1];
    const float* gcn1_W  = (const float*)d_in[2];
    const float* gcn1_b  = (const float*)d_in[3];
    const float* bn1_g   = (const float*)d_in[4];
    const float* bn1_b   = (const float*)d_in[5];
    const float* bn1_m   = (const float*)d_in[6];
    const float* bn1_v   = (const float*)d_in[7];
    const float* gat1_W  = (const float*)d_in[8];
    const float* gat1_as = (const float*)d_in[9];
    const float* gat1_ad = (const float*)d_in[10];
    const float* gat1_b  = (const float*)d_in[11];
    const float* gcn2_W  = (const float*)d_in[12];
    const float* gcn2_b  = (const float*)d_in[13];
    const float* bn2_g   = (const float*)d_in[14];
    const float* bn2_b   = (const float*)d_in[15];
    const float* bn2_m   = (const float*)d_in[16];
    const float* bn2_v   = (const float*)d_in[17];
    const float* gat2_W  = (const float*)d_in[18];
    const float* gat2_as = (const float*)d_in[19];
    const float* gat2_ad = (const float*)d_in[20];
    const float* gat2_b  = (const float*)d_in[21];

    const int n = NNODES;
    const int E = in_sizes[1] / 2;
    const int* src = ei;
    const int* dst = ei + E;

    // ---- workspace carve (16B-aligned chunks) ----
    char* p = (char*)d_ws;
    float* dinv    = (float*)p; p += 50048 * 4;
    int*   degi    = (int*)p;   p += 50048 * 4;
    int*   row_ptr = (int*)p;   p += 50052 * 4;
    int*   cursor  = (int*)p;   p += 50048 * 4;
    int*   csr_src = (int*)p;   p += 800000 * 4;
    unsigned short* hbf = (unsigned short*)p; p += 9600000 * 2;  // bf16 h table [N,<=192]
    float* bufA    = (float*)p; p += 9600000 * 4;                // f32 layer activations
    float* alS     = (float*)p; p += 100096 * 4;
    float* alD     = (float*)p; p += 100096 * 4;
    float* selfw   = (float*)p; p += 100096 * 4;
    float* invden  = (float*)p; p += 100096 * 4;
    float* eex     = (float*)p; p += 1600000 * 4;

    const int B = 256;
    const int GB = nblk(n, 64);
    float* out = (float*)d_out;

    // ---- CSR build (shared by all 4 graph layers) ----
    k_zero_deg<<<nblk(n, B), B, 0, stream>>>(degi, n);
    k_count<<<nblk(E, B), B, 0, stream>>>(dst, degi, E);
    k_dinv<<<nblk(n, B), B, 0, stream>>>(degi, dinv, n);
    k_scan<<<1, 1024, 0, stream>>>(degi, row_ptr, cursor, n);
    k_fill<<<nblk(E, B), B, 0, stream>>>(src, dst, cursor, csr_src, E);

    // ---- GCN1: x[N,128] @ W[128,96] -> bf16 -> gather -> BN1+relu (f32) ----
    k_gemm_tile<3><<<GB, 256, 0, stream>>>(x, gcn1_W, hbf, n, 128, 96);
    k_gcn_gather_bn8<<<nblk((long long)n * 12, B), B, 0, stream>>>(
        (const uint4*)hbf, row_ptr, csr_src, dinv, gcn1_b, bn1_g, bn1_b, bn1_m, bn1_v,
        (float4*)bufA, n, 12);

    // ---- GAT1: h[N,96] @ W[96,192] -> bf16, H=2, C=96 ----
    k_gemm_tile<6><<<GB, 256, 0, stream>>>(bufA, gat1_W, hbf, n, 96, 192);
    k_gat_logits8<<<nblk(n * 2, B), B, 0, stream>>>((const uint4*)hbf, gat1_as, gat1_ad, alS, alD, n, 96);
    k_gat_vh<<<nblk(n * 2, B), B, 0, stream>>>(row_ptr, csr_src, alS, alD, eex, selfw, invden, n, 2);
    k_gat_gather2_8<<<nblk((long long)n * 12, B), B, 0, stream>>>(
        (const uint4*)hbf, row_ptr, csr_src, (const float2*)eex, (const float2*)selfw,
        (const float2*)invden, gat1_b, (float4*)bufA, n, 12, 1);

    // ---- GCN2: h[N,96] @ W[96,96] -> bf16 -> gather -> BN2+relu ----
    k_gemm_tile<3><<<GB, 256, 0, stream>>>(bufA, gcn2_W, hbf, n, 96, 96);
    k_gcn_gather_bn8<<<nblk((long long)n * 12, B), B, 0, stream>>>(
        (const uint4*)hbf, row_ptr, csr_src, dinv, gcn2_b, bn2_g, bn2_b, bn2_m, bn2_v,
        (float4*)bufA, n, 12);

    // ---- GAT2: h[N,96] @ W[96,80] -> bf16, H=2, C=40 ----
    k_gemm_tile<3><<<GB, 256, 0, stream>>>(bufA, gat2_W, hbf, n, 96, 80);
    k_gat_logits8<<<nblk(n * 2, B), B, 0, stream>>>((const uint4*)hbf, gat2_as, gat2_ad, alS, alD, n, 40);
    k_gat_vh<<<nblk(n * 2, B), B, 0, stream>>>(row_ptr, csr_src, alS, alD, eex, selfw, invden, n, 2);
    k_gat_gather2_8<<<nblk((long long)n * 5, B), B, 0, stream>>>(
        (const uint4*)hbf, row_ptr, csr_src, (const float2*)eex, (const float2*)selfw,
        (const float2*)invden, gat2_b, (float4*)bufA, n, 5, 0);

    // ---- log_softmax -> d_out ----
    k_logsoftmax40<<<nblk(n, B), B, 0, stream>>>(bufA, out, n);
}

// Round 6
// 495.989 us; speedup vs baseline: 4.3817x; 1.1778x over previous
//
#include <hip/hip_runtime.h>
#include <math.h>

#define NNODES 50000
#define NEG_SLOPE 0.2f
#define BN_EPS 1e-5f

static __device__ __forceinline__ float leaky(float x) {
    return x > 0.f ? x : NEG_SLOPE * x;
}
// f32 -> bf16 (RNE)
static __device__ __forceinline__ unsigned short f2bf(float x) {
    unsigned u = __float_as_uint(x);
    u += 0x7FFFu + ((u >> 16) & 1u);
    return (unsigned short)(u >> 16);
}
// unpack 8 bf16 (uint4) -> 8 f32
static __device__ __forceinline__ void unpack8(uint4 u, float* v) {
    v[0] = __uint_as_float(u.x << 16);
    v[1] = __uint_as_float(u.x & 0xFFFF0000u);
    v[2] = __uint_as_float(u.y << 16);
    v[3] = __uint_as_float(u.y & 0xFFFF0000u);
    v[4] = __uint_as_float(u.z << 16);
    v[5] = __uint_as_float(u.z & 0xFFFF0000u);
    v[6] = __uint_as_float(u.w << 16);
    v[7] = __uint_as_float(u.w & 0xFFFF0000u);
}
static __device__ __forceinline__ void acc8(uint4 u, float w, float* a) {
    float v[8]; unpack8(u, v);
#pragma unroll
    for (int j = 0; j < 8; ++j) a[j] = fmaf(w, v[j], a[j]);
}

// ---------------- CSR build ----------------
__global__ void k_zero_deg(int* degi, int n) {
    int v = blockIdx.x * blockDim.x + threadIdx.x;
    if (v < n) degi[v] = 0;
}
__global__ void k_count(const int* __restrict__ dst, int* degi, int E) {
    int e = blockIdx.x * blockDim.x + threadIdx.x;
    if (e < E) atomicAdd(&degi[dst[e]], 1);
}
// 3-phase parallel scan over degi[n]
__global__ void k_scan1(const int* __restrict__ degi, int* __restrict__ incl,
                        int* __restrict__ bsum, int n) {
    __shared__ int s[256];
    int i = blockIdx.x * 256 + threadIdx.x;
    int v = (i < n) ? degi[i] : 0;
    s[threadIdx.x] = v;
    __syncthreads();
    for (int off = 1; off < 256; off <<= 1) {
        int t = (threadIdx.x >= (unsigned)off) ? s[threadIdx.x - off] : 0;
        __syncthreads();
        s[threadIdx.x] += t;
        __syncthreads();
    }
    if (i < n) incl[i] = s[threadIdx.x];
    if (threadIdx.x == 255) bsum[blockIdx.x] = s[255];
}
__global__ void k_scan2(int* bsum, int nb) {  // nb <= 256, single block
    __shared__ int s[256];
    int v = ((int)threadIdx.x < nb) ? bsum[threadIdx.x] : 0;
    s[threadIdx.x] = v;
    __syncthreads();
    for (int off = 1; off < 256; off <<= 1) {
        int t = (threadIdx.x >= (unsigned)off) ? s[threadIdx.x - off] : 0;
        __syncthreads();
        s[threadIdx.x] += t;
        __syncthreads();
    }
    if ((int)threadIdx.x < nb) bsum[threadIdx.x] = s[threadIdx.x];  // inclusive
}
// offsets + row_ptr/cursor + dinv fold-in
__global__ void k_scan3(const int* __restrict__ degi, const int* __restrict__ incl,
                        const int* __restrict__ bsum, int* __restrict__ row_ptr,
                        int* __restrict__ cursor, float* __restrict__ dinv, int n) {
    int i = blockIdx.x * 256 + threadIdx.x;
    if (i >= n) return;
    int off = (blockIdx.x > 0) ? bsum[blockIdx.x - 1] : 0;
    int inc = incl[i] + off;
    row_ptr[i + 1] = inc;
    cursor[i] = inc - degi[i];
    dinv[i] = rsqrtf((float)(degi[i] + 1));  // +1 self-loop
    if (i == 0) row_ptr[0] = 0;
}
__global__ void k_fill(const int* __restrict__ src, const int* __restrict__ dst,
                       int* cursor, int* __restrict__ csr_src, int E) {
    int e = blockIdx.x * blockDim.x + threadIdx.x;
    if (e >= E) return;
    int pos = atomicAdd(&cursor[dst[e]], 1);
    csr_src[pos] = src[e];
}

// ---------------- tiled GEMM, bf16 output ----------------
template<int TN>
__launch_bounds__(256)
__global__ void k_gemm_tile(const float* __restrict__ A, const float* __restrict__ W,
                            unsigned short* __restrict__ C, int n, int Ki, int Ko) {
    constexpr int KOP = 32 * TN;
    __shared__ float a_s[16][64];
    __shared__ float w_s[16][KOP];
    const int t = threadIdx.x;
    const int tx = t & 31, ty = t >> 5;
    const int row0 = blockIdx.x * 64;
    const int lrow = t & 63, lkq = t >> 6;

    float acc[8][TN];
#pragma unroll
    for (int i = 0; i < 8; ++i)
#pragma unroll
        for (int j = 0; j < TN; ++j) acc[i][j] = 0.f;

    for (int k0 = 0; k0 < Ki; k0 += 16) {
        {
            int r = row0 + lrow;
            float4 av = make_float4(0.f, 0.f, 0.f, 0.f);
            if (r < n) av = *(const float4*)&A[(long long)r * Ki + k0 + lkq * 4];
            a_s[lkq * 4 + 0][lrow] = av.x;
            a_s[lkq * 4 + 1][lrow] = av.y;
            a_s[lkq * 4 + 2][lrow] = av.z;
            a_s[lkq * 4 + 3][lrow] = av.w;
        }
        for (int base = 0; base < 16 * KOP; base += 256) {
            int idx = base + t;
            int kk = idx / KOP, c = idx % KOP;
            w_s[kk][c] = (c < Ko) ? W[(k0 + kk) * Ko + c] : 0.f;
        }
        __syncthreads();
#pragma unroll 4
        for (int kk = 0; kk < 16; ++kk) {
            float a_r[8];
            *(float4*)&a_r[0] = *(const float4*)&a_s[kk][ty * 8];
            *(float4*)&a_r[4] = *(const float4*)&a_s[kk][ty * 8 + 4];
            float w_r[TN];
#pragma unroll
            for (int j = 0; j < TN; ++j) w_r[j] = w_s[kk][tx * TN + j];
#pragma unroll
            for (int i = 0; i < 8; ++i)
#pragma unroll
                for (int j = 0; j < TN; ++j)
                    acc[i][j] = fmaf(a_r[i], w_r[j], acc[i][j]);
        }
        __syncthreads();
    }
#pragma unroll
    for (int i = 0; i < 8; ++i) {
        int r = row0 + ty * 8 + i;
        if (r >= n) continue;
#pragma unroll
        for (int j = 0; j < TN; ++j) {
            int c = tx * TN + j;
            if (c < Ko) C[(long long)r * Ko + c] = f2bf(acc[i][j]);
        }
    }
}

// ---------------- GCN gather (bf16 in, 8ch/thread) + bias + BN + relu ----------------
__global__ void k_gcn_gather_bn8(const uint4* __restrict__ hb, const int* __restrict__ row_ptr,
                                 const int* __restrict__ csr_src, const float* __restrict__ dinv,
                                 const float* __restrict__ bias, const float* __restrict__ g,
                                 const float* __restrict__ b, const float* __restrict__ m,
                                 const float* __restrict__ vv,
                                 float4* __restrict__ out4, int n, int Q8) {
    int t = blockIdx.x * blockDim.x + threadIdx.x;
    if (t >= n * Q8) return;
    int v = t / Q8, q = t % Q8;
    int beg = row_ptr[v], end = row_ptr[v + 1];
    float dv = dinv[v];
    float a[8] = {0.f, 0.f, 0.f, 0.f, 0.f, 0.f, 0.f, 0.f};
    acc8(hb[(long long)v * Q8 + q], dv, a);
    for (int p = beg; p < end; ++p) {
        int s = csr_src[p];
        acc8(hb[(long long)s * Q8 + q], dinv[s], a);
    }
    int c0 = q * 8;
    float o[8];
#pragma unroll
    for (int j = 0; j < 8; ++j) {
        int c = c0 + j;
        float x = fmaf(a[j], dv, bias[c]);
        x = (x - m[c]) * rsqrtf(vv[c] + BN_EPS) * g[c] + b[c];
        o[j] = fmaxf(x, 0.f);
    }
    long long ob = (long long)v * (Q8 * 2) + q * 2;
    out4[ob]     = make_float4(o[0], o[1], o[2], o[3]);
    out4[ob + 1] = make_float4(o[4], o[5], o[6], o[7]);
}

// ---------------- GAT ----------------
__global__ void k_gat_logits8(const uint4* __restrict__ hb, const float* __restrict__ as,
                              const float* __restrict__ ad, float* __restrict__ alS,
                              float* __restrict__ alD, int n, int C) {
    int t = blockIdx.x * blockDim.x + threadIdx.x;
    if (t >= n * 2) return;
    int hh = t & 1;
    int C8 = C >> 3;
    const uint4* row = hb + (long long)t * C8;  // [N, 2, C8]
    float s1 = 0.f, s2 = 0.f;
    for (int q = 0; q < C8; ++q) {
        float v[8]; unpack8(row[q], v);
#pragma unroll
        for (int j = 0; j < 8; ++j) {
            int c = hh * C + q * 8 + j;
            s1 = fmaf(v[j], as[c], s1);
            s2 = fmaf(v[j], ad[c], s2);
        }
    }
    alS[t] = s1; alD[t] = s2;
}
__global__ void k_gat_vh(const int* __restrict__ row_ptr, const int* __restrict__ csr_src,
                         const float* __restrict__ alS, const float* __restrict__ alD,
                         float* __restrict__ eex, float* __restrict__ selfw,
                         float* __restrict__ invden, int n, int H) {
    int t = blockIdx.x * blockDim.x + threadIdx.x;
    if (t >= n * H) return;
    int v = t / H, h = t % H;
    int beg = row_ptr[v], end = row_ptr[v + 1];
    float ad = alD[t];
    float l_self = leaky(alS[t] + ad);
    float mx = l_self;
    for (int p = beg; p < end; ++p) {
        int s = csr_src[p];
        float l = leaky(alS[s * H + h] + ad);
        eex[p * H + h] = l;
        mx = fmaxf(mx, l);
    }
    float exs = expf(l_self - mx);
    float den = exs;
    for (int p = beg; p < end; ++p) {
        float ex = expf(eex[p * H + h] - mx);
        eex[p * H + h] = ex;
        den += ex;
    }
    selfw[t] = exs;
    invden[t] = 1.f / den;
}
__global__ void k_gat_gather2_8(const uint4* __restrict__ hb, const int* __restrict__ row_ptr,
                                const int* __restrict__ csr_src, const float2* __restrict__ eex2,
                                const float2* __restrict__ selfw2, const float2* __restrict__ invden2,
                                const float* __restrict__ bias, float4* __restrict__ out4,
                                int n, int Q8, int do_relu) {
    int t = blockIdx.x * blockDim.x + threadIdx.x;
    if (t >= n * Q8) return;
    int v = t / Q8, q = t % Q8;
    int rowOct = 2 * Q8;
    int beg = row_ptr[v], end = row_ptr[v + 1];
    float A0[8] = {0,0,0,0,0,0,0,0}, A1[8] = {0,0,0,0,0,0,0,0};
    {
        float2 sw = selfw2[v];
        const uint4* hv = hb + (long long)v * rowOct;
        acc8(hv[q], sw.x, A0);
        acc8(hv[Q8 + q], sw.y, A1);
    }
    for (int p = beg; p < end; ++p) {
        int s = csr_src[p];
        float2 w = eex2[p];
        const uint4* hs = hb + (long long)s * rowOct;
        acc8(hs[q], w.x, A0);
        acc8(hs[Q8 + q], w.y, A1);
    }
    float2 idn = invden2[v];
    int c0 = q * 8;
    float o[8];
#pragma unroll
    for (int j = 0; j < 8; ++j) {
        float x = fmaf(0.5f, fmaf(A0[j], idn.x, A1[j] * idn.y), bias[c0 + j]);
        o[j] = do_relu ? fmaxf(x, 0.f) : x;
    }
    long long ob = (long long)v * (Q8 * 2) + q * 2;
    out4[ob]     = make_float4(o[0], o[1], o[2], o[3]);
    out4[ob + 1] = make_float4(o[4], o[5], o[6], o[7]);
}

__global__ void k_logsoftmax40(const float* __restrict__ in, float* __restrict__ out, int n) {
    int v = blockIdx.x * blockDim.x + threadIdx.x;
    if (v >= n) return;
    float vals[40];
    float mx = -INFINITY;
#pragma unroll
    for (int c = 0; c < 40; ++c) {
        float x = in[v * 40 + c];
        vals[c] = x;
        mx = fmaxf(mx, x);
    }
    float s = 0.f;
#pragma unroll
    for (int c = 0; c < 40; ++c) s += expf(vals[c] - mx);
    float ls = logf(s);
#pragma unroll
    for (int c = 0; c < 40; ++c) out[v * 40 + c] = vals[c] - mx - ls;
}

static inline int nblk(long long n, int b) { return (int)((n + b - 1) / b); }

extern "C" void kernel_launch(void* const* d_in, const int* in_sizes, int n_in,
                              void* d_out, int out_size, void* d_ws, size_t ws_size,
                              hipStream_t stream) {
    const float* x       = (const float*)d_in[0];
    const int*   ei      = (const int*)d_in[1];
    const float* gcn1_W  = (const float*)d_in[2];
    const float* gcn1_b  = (const float*)d_in[3];
    const float* bn1_g   = (const float*)d_in[4];
    const float* bn1_b   = (const float*)d_in[5];
    const float* bn1_m   = (const float*)d_in[6];
    const float* bn1_v   = (const float*)d_in[7];
    const float* gat1_W  = (const float*)d_in[8];
    const float* gat1_as = (const float*)d_in[9];
    const float* gat1_ad = (const float*)d_in[10];
    const float* gat1_b  = (const float*)d_in[11];
    const float* gcn2_W  = (const float*)d_in[12];
    const float* gcn2_b  = (const float*)d_in[13];
    const float* bn2_g   = (const float*)d_in[14];
    const float* bn2_b   = (const float*)d_in[15];
    const float* bn2_m   = (const float*)d_in[16];
    const float* bn2_v   = (const float*)d_in[17];
    const float* gat2_W  = (const float*)d_in[18];
    const float* gat2_as = (const float*)d_in[19];
    const float* gat2_ad = (const float*)d_in[20];
    const float* gat2_b  = (const float*)d_in[21];

    const int n = NNODES;
    const int E = in_sizes[1] / 2;
    const int* src = ei;
    const int* dst = ei + E;

    // ---- workspace carve (16B-aligned chunks) ----
    char* p = (char*)d_ws;
    float* dinv    = (float*)p; p += 50048 * 4;
    int*   degi    = (int*)p;   p += 50048 * 4;
    int*   row_ptr = (int*)p;   p += 50052 * 4;
    int*   cursor  = (int*)p;   p += 50048 * 4;
    int*   incl    = (int*)p;   p += 50048 * 4;
    int*   bsum    = (int*)p;   p += 256 * 4;
    int*   csr_src = (int*)p;   p += 800000 * 4;
    unsigned short* hbf = (unsigned short*)p; p += 9600000 * 2;  // bf16 h table [N,<=192]
    float* bufA    = (float*)p; p += 9600000 * 4;                // f32 layer activations
    float* alS     = (float*)p; p += 100096 * 4;
    float* alD     = (float*)p; p += 100096 * 4;
    float* selfw   = (float*)p; p += 100096 * 4;
    float* invden  = (float*)p; p += 100096 * 4;
    float* eex     = (float*)p; p += 1600000 * 4;

    const int B = 256;
    const int GB = nblk(n, 64);
    const int SB = nblk(n, 256);  // scan blocks (196 <= 256)
    float* out = (float*)d_out;

    // ---- CSR build (shared by all 4 graph layers) ----
    k_zero_deg<<<nblk(n, B), B, 0, stream>>>(degi, n);
    k_count<<<nblk(E, B), B, 0, stream>>>(dst, degi, E);
    k_scan1<<<SB, 256, 0, stream>>>(degi, incl, bsum, n);
    k_scan2<<<1, 256, 0, stream>>>(bsum, SB);
    k_scan3<<<SB, 256, 0, stream>>>(degi, incl, bsum, row_ptr, cursor, dinv, n);
    k_fill<<<nblk(E, B), B, 0, stream>>>(src, dst, cursor, csr_src, E);

    // ---- GCN1: x[N,128] @ W[128,96] -> bf16 -> gather -> BN1+relu (f32) ----
    k_gemm_tile<3><<<GB, 256, 0, stream>>>(x, gcn1_W, hbf, n, 128, 96);
    k_gcn_gather_bn8<<<nblk((long long)n * 12, B), B, 0, stream>>>(
        (const uint4*)hbf, row_ptr, csr_src, dinv, gcn1_b, bn1_g, bn1_b, bn1_m, bn1_v,
        (float4*)bufA, n, 12);

    // ---- GAT1: h[N,96] @ W[96,192] -> bf16, H=2, C=96 ----
    k_gemm_tile<6><<<GB, 256, 0, stream>>>(bufA, gat1_W, hbf, n, 96, 192);
    k_gat_logits8<<<nblk(n * 2, B), B, 0, stream>>>((const uint4*)hbf, gat1_as, gat1_ad, alS, alD, n, 96);
    k_gat_vh<<<nblk(n * 2, B), B, 0, stream>>>(row_ptr, csr_src, alS, alD, eex, selfw, invden, n, 2);
    k_gat_gather2_8<<<nblk((long long)n * 12, B), B, 0, stream>>>(
        (const uint4*)hbf, row_ptr, csr_src, (const float2*)eex, (const float2*)selfw,
        (const float2*)invden, gat1_b, (float4*)bufA, n, 12, 1);

    // ---- GCN2: h[N,96] @ W[96,96] -> bf16 -> gather -> BN2+relu ----
    k_gemm_tile<3><<<GB, 256, 0, stream>>>(bufA, gcn2_W, hbf, n, 96, 96);
    k_gcn_gather_bn8<<<nblk((long long)n * 12, B), B, 0, stream>>>(
        (const uint4*)hbf, row_ptr, csr_src, dinv, gcn2_b, bn2_g, bn2_b, bn2_m, bn2_v,
        (float4*)bufA, n, 12);

    // ---- GAT2: h[N,96] @ W[96,80] -> bf16, H=2, C=40 ----
    k_gemm_tile<3><<<GB, 256, 0, stream>>>(bufA, gat2_W, hbf, n, 96, 80);
    k_gat_logits8<<<nblk(n * 2, B), B, 0, stream>>>((const uint4*)hbf, gat2_as, gat2_ad, alS, alD, n, 40);
    k_gat_vh<<<nblk(n * 2, B), B, 0, stream>>>(row_ptr, csr_src, alS, alD, eex, selfw, invden, n, 2);
    k_gat_gather2_8<<<nblk((long long)n * 5, B), B, 0, stream>>>(
        (const uint4*)hbf, row_ptr, csr_src, (const float2*)eex, (const float2*)selfw,
        (const float2*)invden, gat2_b, (float4*)bufA, n, 5, 0);

    // ---- log_softmax -> d_out ----
    k_logsoftmax40<<<nblk(n, B), B, 0, stream>>>(bufA, out, n);
}

// Round 7
// 462.209 us; speedup vs baseline: 4.7020x; 1.0731x over previous
//
#include <hip/hip_runtime.h>
#include <math.h>

#define NNODES 50000
#define NEG_SLOPE 0.2f
#define BN_EPS 1e-5f

static __device__ __forceinline__ float leaky(float x) {
    return x > 0.f ? x : NEG_SLOPE * x;
}
// f32 -> bf16 (RNE)
static __device__ __forceinline__ unsigned short f2bf(float x) {
    unsigned u = __float_as_uint(x);
    u += 0x7FFFu + ((u >> 16) & 1u);
    return (unsigned short)(u >> 16);
}
// unpack 8 bf16 (uint4) -> 8 f32
static __device__ __forceinline__ void unpack8(uint4 u, float* v) {
    v[0] = __uint_as_float(u.x << 16);
    v[1] = __uint_as_float(u.x & 0xFFFF0000u);
    v[2] = __uint_as_float(u.y << 16);
    v[3] = __uint_as_float(u.y & 0xFFFF0000u);
    v[4] = __uint_as_float(u.z << 16);
    v[5] = __uint_as_float(u.z & 0xFFFF0000u);
    v[6] = __uint_as_float(u.w << 16);
    v[7] = __uint_as_float(u.w & 0xFFFF0000u);
}
static __device__ __forceinline__ void acc8(uint4 u, float w, float* a) {
    float v[8]; unpack8(u, v);
#pragma unroll
    for (int j = 0; j < 8; ++j) a[j] = fmaf(w, v[j], a[j]);
}

// ---------------- CSR build ----------------
__global__ void k_zero_deg(int* degi, int n) {
    int v = blockIdx.x * blockDim.x + threadIdx.x;
    if (v < n) degi[v] = 0;
}
__global__ void k_count(const int* __restrict__ dst, int* degi, int E) {
    int e = blockIdx.x * blockDim.x + threadIdx.x;
    if (e < E) atomicAdd(&degi[dst[e]], 1);
}
// 3-phase parallel scan over degi[n]
__global__ void k_scan1(const int* __restrict__ degi, int* __restrict__ incl,
                        int* __restrict__ bsum, int n) {
    __shared__ int s[256];
    int i = blockIdx.x * 256 + threadIdx.x;
    int v = (i < n) ? degi[i] : 0;
    s[threadIdx.x] = v;
    __syncthreads();
    for (int off = 1; off < 256; off <<= 1) {
        int t = (threadIdx.x >= (unsigned)off) ? s[threadIdx.x - off] : 0;
        __syncthreads();
        s[threadIdx.x] += t;
        __syncthreads();
    }
    if (i < n) incl[i] = s[threadIdx.x];
    if (threadIdx.x == 255) bsum[blockIdx.x] = s[255];
}
__global__ void k_scan2(int* bsum, int nb) {  // nb <= 256, single block
    __shared__ int s[256];
    int v = ((int)threadIdx.x < nb) ? bsum[threadIdx.x] : 0;
    s[threadIdx.x] = v;
    __syncthreads();
    for (int off = 1; off < 256; off <<= 1) {
        int t = (threadIdx.x >= (unsigned)off) ? s[threadIdx.x - off] : 0;
        __syncthreads();
        s[threadIdx.x] += t;
        __syncthreads();
    }
    if ((int)threadIdx.x < nb) bsum[threadIdx.x] = s[threadIdx.x];  // inclusive
}
__global__ void k_scan3(const int* __restrict__ degi, const int* __restrict__ incl,
                        const int* __restrict__ bsum, int* __restrict__ row_ptr,
                        int* __restrict__ cursor, float* __restrict__ dinv, int n) {
    int i = blockIdx.x * 256 + threadIdx.x;
    if (i >= n) return;
    int off = (blockIdx.x > 0) ? bsum[blockIdx.x - 1] : 0;
    int inc = incl[i] + off;
    row_ptr[i + 1] = inc;
    cursor[i] = inc - degi[i];
    dinv[i] = rsqrtf((float)(degi[i] + 1));  // +1 self-loop
    if (i == 0) row_ptr[0] = 0;
}
__global__ void k_fill(const int* __restrict__ src, const int* __restrict__ dst,
                       int* cursor, int* __restrict__ csr_src, int E) {
    int e = blockIdx.x * blockDim.x + threadIdx.x;
    if (e >= E) return;
    int pos = atomicAdd(&cursor[dst[e]], 1);
    csr_src[pos] = src[e];
}

// ---------------- tiled GEMM, bf16 output ----------------
template<int TN>
__launch_bounds__(256)
__global__ void k_gemm_tile(const float* __restrict__ A, const float* __restrict__ W,
                            unsigned short* __restrict__ C, int n, int Ki, int Ko) {
    constexpr int KOP = 32 * TN;
    __shared__ float a_s[16][64];
    __shared__ float w_s[16][KOP];
    const int t = threadIdx.x;
    const int tx = t & 31, ty = t >> 5;
    const int row0 = blockIdx.x * 64;
    const int lrow = t & 63, lkq = t >> 6;

    float acc[8][TN];
#pragma unroll
    for (int i = 0; i < 8; ++i)
#pragma unroll
        for (int j = 0; j < TN; ++j) acc[i][j] = 0.f;

    for (int k0 = 0; k0 < Ki; k0 += 16) {
        {
            int r = row0 + lrow;
            float4 av = make_float4(0.f, 0.f, 0.f, 0.f);
            if (r < n) av = *(const float4*)&A[(long long)r * Ki + k0 + lkq * 4];
            a_s[lkq * 4 + 0][lrow] = av.x;
            a_s[lkq * 4 + 1][lrow] = av.y;
            a_s[lkq * 4 + 2][lrow] = av.z;
            a_s[lkq * 4 + 3][lrow] = av.w;
        }
        for (int base = 0; base < 16 * KOP; base += 256) {
            int idx = base + t;
            int kk = idx / KOP, c = idx % KOP;
            w_s[kk][c] = (c < Ko) ? W[(k0 + kk) * Ko + c] : 0.f;
        }
        __syncthreads();
#pragma unroll 4
        for (int kk = 0; kk < 16; ++kk) {
            float a_r[8];
            *(float4*)&a_r[0] = *(const float4*)&a_s[kk][ty * 8];
            *(float4*)&a_r[4] = *(const float4*)&a_s[kk][ty * 8 + 4];
            float w_r[TN];
#pragma unroll
            for (int j = 0; j < TN; ++j) w_r[j] = w_s[kk][tx * TN + j];
#pragma unroll
            for (int i = 0; i < 8; ++i)
#pragma unroll
                for (int j = 0; j < TN; ++j)
                    acc[i][j] = fmaf(a_r[i], w_r[j], acc[i][j]);
        }
        __syncthreads();
    }
#pragma unroll
    for (int i = 0; i < 8; ++i) {
        int r = row0 + ty * 8 + i;
        if (r >= n) continue;
#pragma unroll
        for (int j = 0; j < TN; ++j) {
            int c = tx * TN + j;
            if (c < Ko) C[(long long)r * Ko + c] = f2bf(acc[i][j]);
        }
    }
}

// ---------------- GCN gather (bf16, 8ch/thread, 2-edge unrolled) + BN + relu ----------------
__global__ void k_gcn_gather_bn8(const uint4* __restrict__ hb, const int* __restrict__ row_ptr,
                                 const int* __restrict__ csr_src, const float* __restrict__ dinv,
                                 const float* __restrict__ bias, const float* __restrict__ g,
                                 const float* __restrict__ b, const float* __restrict__ m,
                                 const float* __restrict__ vv,
                                 float4* __restrict__ out4, int n, int Q8) {
    int t = blockIdx.x * blockDim.x + threadIdx.x;
    if (t >= n * Q8) return;
    int v = t / Q8, q = t % Q8;
    int beg = row_ptr[v], end = row_ptr[v + 1];
    float dv = dinv[v];
    float a[8] = {0.f, 0.f, 0.f, 0.f, 0.f, 0.f, 0.f, 0.f};
    acc8(hb[(long long)v * Q8 + q], dv, a);
    int p = beg;
    for (; p + 2 <= end; p += 2) {
        int s0 = csr_src[p], s1 = csr_src[p + 1];
        float w0 = dinv[s0], w1 = dinv[s1];
        uint4 u0 = hb[(long long)s0 * Q8 + q];
        uint4 u1 = hb[(long long)s1 * Q8 + q];
        acc8(u0, w0, a);
        acc8(u1, w1, a);
    }
    if (p < end) {
        int s = csr_src[p];
        acc8(hb[(long long)s * Q8 + q], dinv[s], a);
    }
    int c0 = q * 8;
    float o[8];
#pragma unroll
    for (int j = 0; j < 8; ++j) {
        int c = c0 + j;
        float x = fmaf(a[j], dv, bias[c]);
        x = (x - m[c]) * rsqrtf(vv[c] + BN_EPS) * g[c] + b[c];
        o[j] = fmaxf(x, 0.f);
    }
    long long ob = (long long)v * (Q8 * 2) + q * 2;
    out4[ob]     = make_float4(o[0], o[1], o[2], o[3]);
    out4[ob + 1] = make_float4(o[4], o[5], o[6], o[7]);
}

// ---------------- GAT ----------------
__global__ void k_gat_logits8(const uint4* __restrict__ hb, const float* __restrict__ as,
                              const float* __restrict__ ad, float* __restrict__ alS,
                              float* __restrict__ alD, int n, int C) {
    int t = blockIdx.x * blockDim.x + threadIdx.x;
    if (t >= n * 2) return;
    int hh = t & 1;
    int C8 = C >> 3;
    const uint4* row = hb + (long long)t * C8;  // [N, 2, C8]
    float s1 = 0.f, s2 = 0.f;
    for (int q = 0; q < C8; ++q) {
        float v[8]; unpack8(row[q], v);
#pragma unroll
        for (int j = 0; j < 8; ++j) {
            int c = hh * C + q * 8 + j;
            s1 = fmaf(v[j], as[c], s1);
            s2 = fmaf(v[j], ad[c], s2);
        }
    }
    alS[t] = s1; alD[t] = s2;
}
// two-pass softmax, 2-edge unrolled; pass1 stashes leaky logits in eex
__global__ void k_gat_vh(const int* __restrict__ row_ptr, const int* __restrict__ csr_src,
                         const float* __restrict__ alS, const float* __restrict__ alD,
                         float* __restrict__ eex, float* __restrict__ selfw,
                         float* __restrict__ invden, int n, int H) {
    int t = blockIdx.x * blockDim.x + threadIdx.x;
    if (t >= n * H) return;
    int v = t / H, h = t % H;
    int beg = row_ptr[v], end = row_ptr[v + 1];
    float ad = alD[t];
    float l_self = leaky(alS[t] + ad);
    float mx = l_self;
    int p = beg;
    for (; p + 2 <= end; p += 2) {
        int s0 = csr_src[p], s1 = csr_src[p + 1];
        float l0 = leaky(alS[s0 * H + h] + ad);
        float l1 = leaky(alS[s1 * H + h] + ad);
        eex[p * H + h] = l0;
        eex[(p + 1) * H + h] = l1;
        mx = fmaxf(mx, fmaxf(l0, l1));
    }
    if (p < end) {
        int s = csr_src[p];
        float l = leaky(alS[s * H + h] + ad);
        eex[p * H + h] = l;
        mx = fmaxf(mx, l);
    }
    float exs = expf(l_self - mx);
    float den = exs;
    p = beg;
    for (; p + 2 <= end; p += 2) {
        float e0 = expf(eex[p * H + h] - mx);
        float e1 = expf(eex[(p + 1) * H + h] - mx);
        eex[p * H + h] = e0;
        eex[(p + 1) * H + h] = e1;
        den += e0 + e1;
    }
    if (p < end) {
        float e = expf(eex[p * H + h] - mx);
        eex[p * H + h] = e;
        den += e;
    }
    selfw[t] = exs;
    invden[t] = 1.f / den;
}
// H=2 gather (bf16, 8ch/thread both heads, 2-edge unrolled) + head-mean + bias (+relu)
__global__ void k_gat_gather2_8(const uint4* __restrict__ hb, const int* __restrict__ row_ptr,
                                const int* __restrict__ csr_src, const float2* __restrict__ eex2,
                                const float2* __restrict__ selfw2, const float2* __restrict__ invden2,
                                const float* __restrict__ bias, float4* __restrict__ out4,
                                int n, int Q8, int do_relu) {
    int t = blockIdx.x * blockDim.x + threadIdx.x;
    if (t >= n * Q8) return;
    int v = t / Q8, q = t % Q8;
    int rowOct = 2 * Q8;
    int beg = row_ptr[v], end = row_ptr[v + 1];
    float A0[8] = {0,0,0,0,0,0,0,0}, A1[8] = {0,0,0,0,0,0,0,0};
    {
        float2 sw = selfw2[v];
        const uint4* hv = hb + (long long)v * rowOct;
        acc8(hv[q], sw.x, A0);
        acc8(hv[Q8 + q], sw.y, A1);
    }
    int p = beg;
    for (; p + 2 <= end; p += 2) {
        int s0 = csr_src[p], s1 = csr_src[p + 1];
        float2 w0 = eex2[p], w1 = eex2[p + 1];
        const uint4* h0 = hb + (long long)s0 * rowOct;
        const uint4* h1 = hb + (long long)s1 * rowOct;
        uint4 u00 = h0[q], u01 = h0[Q8 + q];
        uint4 u10 = h1[q], u11 = h1[Q8 + q];
        acc8(u00, w0.x, A0);
        acc8(u01, w0.y, A1);
        acc8(u10, w1.x, A0);
        acc8(u11, w1.y, A1);
    }
    if (p < end) {
        int s = csr_src[p];
        float2 w = eex2[p];
        const uint4* hs = hb + (long long)s * rowOct;
        acc8(hs[q], w.x, A0);
        acc8(hs[Q8 + q], w.y, A1);
    }
    float2 idn = invden2[v];
    int c0 = q * 8;
    float o[8];
#pragma unroll
    for (int j = 0; j < 8; ++j) {
        float x = fmaf(0.5f, fmaf(A0[j], idn.x, A1[j] * idn.y), bias[c0 + j]);
        o[j] = do_relu ? fmaxf(x, 0.f) : x;
    }
    long long ob = (long long)v * (Q8 * 2) + q * 2;
    out4[ob]     = make_float4(o[0], o[1], o[2], o[3]);
    out4[ob + 1] = make_float4(o[4], o[5], o[6], o[7]);
}

__global__ void k_logsoftmax40(const float* __restrict__ in, float* __restrict__ out, int n) {
    int v = blockIdx.x * blockDim.x + threadIdx.x;
    if (v >= n) return;
    float vals[40];
    float mx = -INFINITY;
#pragma unroll
    for (int c = 0; c < 40; ++c) {
        float x = in[v * 40 + c];
        vals[c] = x;
        mx = fmaxf(mx, x);
    }
    float s = 0.f;
#pragma unroll
    for (int c = 0; c < 40; ++c) s += expf(vals[c] - mx);
    float ls = logf(s);
#pragma unroll
    for (int c = 0; c < 40; ++c) out[v * 40 + c] = vals[c] - mx - ls;
}

static inline int nblk(long long n, int b) { return (int)((n + b - 1) / b); }

extern "C" void kernel_launch(void* const* d_in, const int* in_sizes, int n_in,
                              void* d_out, int out_size, void* d_ws, size_t ws_size,
                              hipStream_t stream) {
    const float* x       = (const float*)d_in[0];
    const int*   ei      = (const int*)d_in[1];
    const float* gcn1_W  = (const float*)d_in[2];
    const float* gcn1_b  = (const float*)d_in[3];
    const float* bn1_g   = (const float*)d_in[4];
    const float* bn1_b   = (const float*)d_in[5];
    const float* bn1_m   = (const float*)d_in[6];
    const float* bn1_v   = (const float*)d_in[7];
    const float* gat1_W  = (const float*)d_in[8];
    const float* gat1_as = (const float*)d_in[9];
    const float* gat1_ad = (const float*)d_in[10];
    const float* gat1_b  = (const float*)d_in[11];
    const float* gcn2_W  = (const float*)d_in[12];
    const float* gcn2_b  = (const float*)d_in[13];
    const float* bn2_g   = (const float*)d_in[14];
    const float* bn2_b   = (const float*)d_in[15];
    const float* bn2_m   = (const float*)d_in[16];
    const float* bn2_v   = (const float*)d_in[17];
    const float* gat2_W  = (const float*)d_in[18];
    const float* gat2_as = (const float*)d_in[19];
    const float* gat2_ad = (const float*)d_in[20];
    const float* gat2_b  = (const float*)d_in[21];

    const int n = NNODES;
    const int E = in_sizes[1] / 2;
    const int* src = ei;
    const int* dst = ei + E;

    // ---- workspace carve (16B-aligned chunks) ----
    char* p = (char*)d_ws;
    float* dinv    = (float*)p; p += 50048 * 4;
    int*   degi    = (int*)p;   p += 50048 * 4;
    int*   row_ptr = (int*)p;   p += 50052 * 4;
    int*   cursor  = (int*)p;   p += 50048 * 4;
    int*   incl    = (int*)p;   p += 50048 * 4;
    int*   bsum    = (int*)p;   p += 256 * 4;
    int*   csr_src = (int*)p;   p += 800000 * 4;
    unsigned short* hbf = (unsigned short*)p; p += 9600000 * 2;  // bf16 h table [N,<=192]
    float* bufA    = (float*)p; p += 9600000 * 4;                // f32 layer activations
    float* alS     = (float*)p; p += 100096 * 4;
    float* alD     = (float*)p; p += 100096 * 4;
    float* selfw   = (float*)p; p += 100096 * 4;
    float* invden  = (float*)p; p += 100096 * 4;
    float* eex     = (float*)p; p += 1600000 * 4;

    const int B = 256;
    const int GB = nblk(n, 64);
    const int SB = nblk(n, 256);  // scan blocks (196 <= 256)
    float* out = (float*)d_out;

    // ---- CSR build (shared by all 4 graph layers) ----
    k_zero_deg<<<nblk(n, B), B, 0, stream>>>(degi, n);
    k_count<<<nblk(E, B), B, 0, stream>>>(dst, degi, E);
    k_scan1<<<SB, 256, 0, stream>>>(degi, incl, bsum, n);
    k_scan2<<<1, 256, 0, stream>>>(bsum, SB);
    k_scan3<<<SB, 256, 0, stream>>>(degi, incl, bsum, row_ptr, cursor, dinv, n);
    k_fill<<<nblk(E, B), B, 0, stream>>>(src, dst, cursor, csr_src, E);

    // ---- GCN1: x[N,128] @ W[128,96] -> bf16 -> gather -> BN1+relu (f32) ----
    k_gemm_tile<3><<<GB, 256, 0, stream>>>(x, gcn1_W, hbf, n, 128, 96);
    k_gcn_gather_bn8<<<nblk((long long)n * 12, B), B, 0, stream>>>(
        (const uint4*)hbf, row_ptr, csr_src, dinv, gcn1_b, bn1_g, bn1_b, bn1_m, bn1_v,
        (float4*)bufA, n, 12);

    // ---- GAT1: h[N,96] @ W[96,192] -> bf16, H=2, C=96 ----
    k_gemm_tile<6><<<GB, 256, 0, stream>>>(bufA, gat1_W, hbf, n, 96, 192);
    k_gat_logits8<<<nblk(n * 2, B), B, 0, stream>>>((const uint4*)hbf, gat1_as, gat1_ad, alS, alD, n, 96);
    k_gat_vh<<<nblk(n * 2, B), B, 0, stream>>>(row_ptr, csr_src, alS, alD, eex, selfw, invden, n, 2);
    k_gat_gather2_8<<<nblk((long long)n * 12, B), B, 0, stream>>>(
        (const uint4*)hbf, row_ptr, csr_src, (const float2*)eex, (const float2*)selfw,
        (const float2*)invden, gat1_b, (float4*)bufA, n, 12, 1);

    // ---- GCN2: h[N,96] @ W[96,96] -> bf16 -> gather -> BN2+relu ----
    k_gemm_tile<3><<<GB, 256, 0, stream>>>(bufA, gcn2_W, hbf, n, 96, 96);
    k_gcn_gather_bn8<<<nblk((long long)n * 12, B), B, 0, stream>>>(
        (const uint4*)hbf, row_ptr, csr_src, dinv, gcn2_b, bn2_g, bn2_b, bn2_m, bn2_v,
        (float4*)bufA, n, 12);

    // ---- GAT2: h[N,96] @ W[96,80] -> bf16, H=2, C=40 ----
    k_gemm_tile<3><<<GB, 256, 0, stream>>>(bufA, gat2_W, hbf, n, 96, 80);
    k_gat_logits8<<<nblk(n * 2, B), B, 0, stream>>>((const uint4*)hbf, gat2_as, gat2_ad, alS, alD, n, 40);
    k_gat_vh<<<nblk(n * 2, B), B, 0, stream>>>(row_ptr, csr_src, alS, alD, eex, selfw, invden, n, 2);
    k_gat_gather2_8<<<nblk((long long)n * 5, B), B, 0, stream>>>(
        (const uint4*)hbf, row_ptr, csr_src, (const float2*)eex, (const float2*)selfw,
        (const float2*)invden, gat2_b, (float4*)bufA, n, 5, 0);

    // ---- log_softmax -> d_out ----
    k_logsoftmax40<<<nblk(n, B), B, 0, stream>>>(bufA, out, n);
}

// Round 8
// 385.501 us; speedup vs baseline: 5.6376x; 1.1990x over previous
//
#include <hip/hip_runtime.h>
#include <math.h>

#define NNODES 50000
#define NEG_SLOPE 0.2f
#define BN_EPS 1e-5f

typedef __attribute__((ext_vector_type(8))) short bf16x8;
typedef __attribute__((ext_vector_type(4))) float f32x4;

static __device__ __forceinline__ float leaky(float x) {
    return x > 0.f ? x : NEG_SLOPE * x;
}
// f32 -> bf16 (RNE)
static __device__ __forceinline__ unsigned short f2bf(float x) {
    unsigned u = __float_as_uint(x);
    u += 0x7FFFu + ((u >> 16) & 1u);
    return (unsigned short)(u >> 16);
}
// unpack 8 bf16 (uint4) -> 8 f32
static __device__ __forceinline__ void unpack8(uint4 u, float* v) {
    v[0] = __uint_as_float(u.x << 16);
    v[1] = __uint_as_float(u.x & 0xFFFF0000u);
    v[2] = __uint_as_float(u.y << 16);
    v[3] = __uint_as_float(u.y & 0xFFFF0000u);
    v[4] = __uint_as_float(u.z << 16);
    v[5] = __uint_as_float(u.z & 0xFFFF0000u);
    v[6] = __uint_as_float(u.w << 16);
    v[7] = __uint_as_float(u.w & 0xFFFF0000u);
}
static __device__ __forceinline__ void acc8(uint4 u, float w, float* a) {
    float v[8]; unpack8(u, v);
#pragma unroll
    for (int j = 0; j < 8; ++j) a[j] = fmaf(w, v[j], a[j]);
}
static __device__ __forceinline__ uint4 pack8(const float* o) {
    uint4 r;
    r.x = ((unsigned)f2bf(o[1]) << 16) | f2bf(o[0]);
    r.y = ((unsigned)f2bf(o[3]) << 16) | f2bf(o[2]);
    r.z = ((unsigned)f2bf(o[5]) << 16) | f2bf(o[4]);
    r.w = ((unsigned)f2bf(o[7]) << 16) | f2bf(o[6]);
    return r;
}

// ---------------- CSR build ----------------
__global__ void k_zero_deg(int* degi, int n) {
    int v = blockIdx.x * blockDim.x + threadIdx.x;
    if (v < n) degi[v] = 0;
}
__global__ void k_count(const int* __restrict__ dst, int* degi, int E) {
    int e = blockIdx.x * blockDim.x + threadIdx.x;
    if (e < E) atomicAdd(&degi[dst[e]], 1);
}
__global__ void k_scan1(const int* __restrict__ degi, int* __restrict__ incl,
                        int* __restrict__ bsum, int n) {
    __shared__ int s[256];
    int i = blockIdx.x * 256 + threadIdx.x;
    int v = (i < n) ? degi[i] : 0;
    s[threadIdx.x] = v;
    __syncthreads();
    for (int off = 1; off < 256; off <<= 1) {
        int t = (threadIdx.x >= (unsigned)off) ? s[threadIdx.x - off] : 0;
        __syncthreads();
        s[threadIdx.x] += t;
        __syncthreads();
    }
    if (i < n) incl[i] = s[threadIdx.x];
    if (threadIdx.x == 255) bsum[blockIdx.x] = s[255];
}
__global__ void k_scan2(int* bsum, int nb) {
    __shared__ int s[256];
    int v = ((int)threadIdx.x < nb) ? bsum[threadIdx.x] : 0;
    s[threadIdx.x] = v;
    __syncthreads();
    for (int off = 1; off < 256; off <<= 1) {
        int t = (threadIdx.x >= (unsigned)off) ? s[threadIdx.x - off] : 0;
        __syncthreads();
        s[threadIdx.x] += t;
        __syncthreads();
    }
    if ((int)threadIdx.x < nb) bsum[threadIdx.x] = s[threadIdx.x];
}
__global__ void k_scan3(const int* __restrict__ degi, const int* __restrict__ incl,
                        const int* __restrict__ bsum, int* __restrict__ row_ptr,
                        int* __restrict__ cursor, float* __restrict__ dinv, int n) {
    int i = blockIdx.x * 256 + threadIdx.x;
    if (i >= n) return;
    int off = (blockIdx.x > 0) ? bsum[blockIdx.x - 1] : 0;
    int inc = incl[i] + off;
    row_ptr[i + 1] = inc;
    cursor[i] = inc - degi[i];
    dinv[i] = rsqrtf((float)(degi[i] + 1));
    if (i == 0) row_ptr[0] = 0;
}
__global__ void k_fill(const int* __restrict__ src, const int* __restrict__ dst,
                       int* cursor, int* __restrict__ csr_src, int E) {
    int e = blockIdx.x * blockDim.x + threadIdx.x;
    if (e >= E) return;
    int pos = atomicAdd(&cursor[dst[e]], 1);
    csr_src[pos] = src[e];
}

// ---------------- weight transpose+convert: WT[c][k] = bf16(W[k][c]) ----------------
__global__ void k_wconv(const float* __restrict__ W, unsigned short* __restrict__ out,
                        int Ki, int Ko) {
    int idx = blockIdx.x * blockDim.x + threadIdx.x;
    if (idx >= Ki * Ko) return;
    int k = idx / Ko, c = idx % Ko;
    out[c * Ki + k] = f2bf(W[idx]);
}
// x f32 -> bf16 (8 elems/thread)
__global__ void k_xconv(const float4* __restrict__ x, uint4* __restrict__ out, int n8) {
    int i = blockIdx.x * blockDim.x + threadIdx.x;
    if (i >= n8) return;
    float4 a = x[i * 2], b = x[i * 2 + 1];
    float o[8] = {a.x, a.y, a.z, a.w, b.x, b.y, b.z, b.w};
    out[i] = pack8(o);
}

// ---------------- MFMA bf16 GEMM: C[n,KO] = A[n,KI] @ W[KI,KO] ----------------
// A bf16 row-major, WT bf16 [KO][KI] (pre-transposed), C bf16.
// 256 thr = 4 waves; block = 64 rows; wave w owns rows w*16..+16, all KO cols.
template<int KI, int KO>
__launch_bounds__(256)
__global__ void k_gemm_mfma(const unsigned short* __restrict__ A,
                            const unsigned short* __restrict__ WT,
                            unsigned short* __restrict__ C, int n) {
    constexpr int KP = KI + 8;       // LDS row pad: +16B keeps reads 2-way-free
    constexpr int NT = KO / 16;      // col tiles per wave
    constexpr int KT = KI / 32;      // k steps
    __shared__ unsigned short wT[KO][KP];
    const int t = threadIdx.x;
    const int w = t >> 6, l = t & 63;

    // stage WT -> LDS (16B chunks)
    constexpr int CH = KI / 8;
    for (int idx = t; idx < KO * CH; idx += 256) {
        int r = idx / CH, o = idx % CH;
        *(uint4*)&wT[r][o * 8] = *(const uint4*)&WT[r * KI + o * 8];
    }
    // prefetch all A fragments (row = l&15, k-quad = l>>4)
    int row = blockIdx.x * 64 + w * 16 + (l & 15);
    bool rv = row < n;
    const unsigned short* ap = A + (long long)row * KI + (l >> 4) * 8;
    bf16x8 afr[KT];
#pragma unroll
    for (int kt = 0; kt < KT; ++kt) {
        bf16x8 z = {};
        afr[kt] = rv ? *(const bf16x8*)(ap + kt * 32) : z;
    }
    __syncthreads();

    f32x4 acc[NT];
#pragma unroll
    for (int ct = 0; ct < NT; ++ct) acc[ct] = (f32x4){0.f, 0.f, 0.f, 0.f};
#pragma unroll
    for (int kt = 0; kt < KT; ++kt) {
#pragma unroll
        for (int ct = 0; ct < NT; ++ct) {
            bf16x8 b = *(const bf16x8*)&wT[ct * 16 + (l & 15)][kt * 32 + (l >> 4) * 8];
            acc[ct] = __builtin_amdgcn_mfma_f32_16x16x32_bf16(afr[kt], b, acc[ct], 0, 0, 0);
        }
    }
    // D: col = l&15, row = (l>>4)*4 + r
    int orow0 = blockIdx.x * 64 + w * 16 + (l >> 4) * 4;
    int col = l & 15;
#pragma unroll
    for (int ct = 0; ct < NT; ++ct) {
#pragma unroll
        for (int r = 0; r < 4; ++r) {
            int rr = orow0 + r;
            if (rr < n) C[(long long)rr * KO + ct * 16 + col] = f2bf(acc[ct][r]);
        }
    }
}

// ---------------- GCN gather (bf16 in/out, 2-edge unrolled) + bias + BN + relu ----------------
__global__ void k_gcn_gather_bn8(const uint4* __restrict__ hb, const int* __restrict__ row_ptr,
                                 const int* __restrict__ csr_src, const float* __restrict__ dinv,
                                 const float* __restrict__ bias, const float* __restrict__ g,
                                 const float* __restrict__ b, const float* __restrict__ m,
                                 const float* __restrict__ vv,
                                 uint4* __restrict__ outb, int n, int Q8) {
    int t = blockIdx.x * blockDim.x + threadIdx.x;
    if (t >= n * Q8) return;
    int v = t / Q8, q = t % Q8;
    int beg = row_ptr[v], end = row_ptr[v + 1];
    float dv = dinv[v];
    float a[8] = {0.f, 0.f, 0.f, 0.f, 0.f, 0.f, 0.f, 0.f};
    acc8(hb[(long long)v * Q8 + q], dv, a);
    int p = beg;
    for (; p + 2 <= end; p += 2) {
        int s0 = csr_src[p], s1 = csr_src[p + 1];
        float w0 = dinv[s0], w1 = dinv[s1];
        uint4 u0 = hb[(long long)s0 * Q8 + q];
        uint4 u1 = hb[(long long)s1 * Q8 + q];
        acc8(u0, w0, a);
        acc8(u1, w1, a);
    }
    if (p < end) {
        int s = csr_src[p];
        acc8(hb[(long long)s * Q8 + q], dinv[s], a);
    }
    int c0 = q * 8;
    float o[8];
#pragma unroll
    for (int j = 0; j < 8; ++j) {
        int c = c0 + j;
        float x = fmaf(a[j], dv, bias[c]);
        x = (x - m[c]) * rsqrtf(vv[c] + BN_EPS) * g[c] + b[c];
        o[j] = fmaxf(x, 0.f);
    }
    outb[(long long)v * Q8 + q] = pack8(o);
}

// ---------------- GAT ----------------
__global__ void k_gat_logits8(const uint4* __restrict__ hb, const float* __restrict__ as,
                              const float* __restrict__ ad, float* __restrict__ alS,
                              float* __restrict__ alD, int n, int C) {
    int t = blockIdx.x * blockDim.x + threadIdx.x;
    if (t >= n * 2) return;
    int hh = t & 1;
    int C8 = C >> 3;
    const uint4* row = hb + (long long)t * C8;
    float s1 = 0.f, s2 = 0.f;
    for (int q = 0; q < C8; ++q) {
        float v[8]; unpack8(row[q], v);
#pragma unroll
        for (int j = 0; j < 8; ++j) {
            int c = hh * C + q * 8 + j;
            s1 = fmaf(v[j], as[c], s1);
            s2 = fmaf(v[j], ad[c], s2);
        }
    }
    alS[t] = s1; alD[t] = s2;
}
__global__ void k_gat_vh(const int* __restrict__ row_ptr, const int* __restrict__ csr_src,
                         const float* __restrict__ alS, const float* __restrict__ alD,
                         float* __restrict__ eex, float* __restrict__ selfw,
                         float* __restrict__ invden, int n, int H) {
    int t = blockIdx.x * blockDim.x + threadIdx.x;
    if (t >= n * H) return;
    int v = t / H, h = t % H;
    int beg = row_ptr[v], end = row_ptr[v + 1];
    float ad = alD[t];
    float l_self = leaky(alS[t] + ad);
    float mx = l_self;
    int p = beg;
    for (; p + 2 <= end; p += 2) {
        int s0 = csr_src[p], s1 = csr_src[p + 1];
        float l0 = leaky(alS[s0 * H + h] + ad);
        float l1 = leaky(alS[s1 * H + h] + ad);
        eex[p * H + h] = l0;
        eex[(p + 1) * H + h] = l1;
        mx = fmaxf(mx, fmaxf(l0, l1));
    }
    if (p < end) {
        int s = csr_src[p];
        float l = leaky(alS[s * H + h] + ad);
        eex[p * H + h] = l;
        mx = fmaxf(mx, l);
    }
    float exs = expf(l_self - mx);
    float den = exs;
    p = beg;
    for (; p + 2 <= end; p += 2) {
        float e0 = expf(eex[p * H + h] - mx);
        float e1 = expf(eex[(p + 1) * H + h] - mx);
        eex[p * H + h] = e0;
        eex[(p + 1) * H + h] = e1;
        den += e0 + e1;
    }
    if (p < end) {
        float e = expf(eex[p * H + h] - mx);
        eex[p * H + h] = e;
        den += e;
    }
    selfw[t] = exs;
    invden[t] = 1.f / den;
}
// H=2 gather (bf16 in, 2-edge unrolled) + head-mean + bias; OUTBF: bf16 or f32 out
template<int OUTBF>
__global__ void k_gat_gather2_8(const uint4* __restrict__ hb, const int* __restrict__ row_ptr,
                                const int* __restrict__ csr_src, const float2* __restrict__ eex2,
                                const float2* __restrict__ selfw2, const float2* __restrict__ invden2,
                                const float* __restrict__ bias, uint4* __restrict__ outb,
                                float4* __restrict__ outf, int n, int Q8, int do_relu) {
    int t = blockIdx.x * blockDim.x + threadIdx.x;
    if (t >= n * Q8) return;
    int v = t / Q8, q = t % Q8;
    int rowOct = 2 * Q8;
    int beg = row_ptr[v], end = row_ptr[v + 1];
    float A0[8] = {0,0,0,0,0,0,0,0}, A1[8] = {0,0,0,0,0,0,0,0};
    {
        float2 sw = selfw2[v];
        const uint4* hv = hb + (long long)v * rowOct;
        acc8(hv[q], sw.x, A0);
        acc8(hv[Q8 + q], sw.y, A1);
    }
    int p = beg;
    for (; p + 2 <= end; p += 2) {
        int s0 = csr_src[p], s1 = csr_src[p + 1];
        float2 w0 = eex2[p], w1 = eex2[p + 1];
        const uint4* h0 = hb + (long long)s0 * rowOct;
        const uint4* h1 = hb + (long long)s1 * rowOct;
        uint4 u00 = h0[q], u01 = h0[Q8 + q];
        uint4 u10 = h1[q], u11 = h1[Q8 + q];
        acc8(u00, w0.x, A0);
        acc8(u01, w0.y, A1);
        acc8(u10, w1.x, A0);
        acc8(u11, w1.y, A1);
    }
    if (p < end) {
        int s = csr_src[p];
        float2 w = eex2[p];
        const uint4* hs = hb + (long long)s * rowOct;
        acc8(hs[q], w.x, A0);
        acc8(hs[Q8 + q], w.y, A1);
    }
    float2 idn = invden2[v];
    int c0 = q * 8;
    float o[8];
#pragma unroll
    for (int j = 0; j < 8; ++j) {
        float x = fmaf(0.5f, fmaf(A0[j], idn.x, A1[j] * idn.y), bias[c0 + j]);
        o[j] = do_relu ? fmaxf(x, 0.f) : x;
    }
    if (OUTBF) {
        outb[(long long)v * Q8 + q] = pack8(o);
    } else {
        long long ob = (long long)v * (Q8 * 2) + q * 2;
        outf[ob]     = make_float4(o[0], o[1], o[2], o[3]);
        outf[ob + 1] = make_float4(o[4], o[5], o[6], o[7]);
    }
}

__global__ void k_logsoftmax40(const float* __restrict__ in, float* __restrict__ out, int n) {
    int v = blockIdx.x * blockDim.x + threadIdx.x;
    if (v >= n) return;
    float vals[40];
    float mx = -INFINITY;
#pragma unroll
    for (int c = 0; c < 40; ++c) {
        float x = in[v * 40 + c];
        vals[c] = x;
        mx = fmaxf(mx, x);
    }
    float s = 0.f;
#pragma unroll
    for (int c = 0; c < 40; ++c) s += expf(vals[c] - mx);
    float ls = logf(s);
#pragma unroll
    for (int c = 0; c < 40; ++c) out[v * 40 + c] = vals[c] - mx - ls;
}

static inline int nblk(long long n, int b) { return (int)((n + b - 1) / b); }

extern "C" void kernel_launch(void* const* d_in, const int* in_sizes, int n_in,
                              void* d_out, int out_size, void* d_ws, size_t ws_size,
                              hipStream_t stream) {
    const float* x       = (const float*)d_in[0];
    const int*   ei      = (const int*)d_in[1];
    const float* gcn1_W  = (const float*)d_in[2];
    const float* gcn1_b  = (const float*)d_in[3];
    const float* bn1_g   = (const float*)d_in[4];
    const float* bn1_b   = (const float*)d_in[5];
    const float* bn1_m   = (const float*)d_in[6];
    const float* bn1_v   = (const float*)d_in[7];
    const float* gat1_W  = (const float*)d_in[8];
    const float* gat1_as = (const float*)d_in[9];
    const float* gat1_ad = (const float*)d_in[10];
    const float* gat1_b  = (const float*)d_in[11];
    const float* gcn2_W  = (const float*)d_in[12];
    const float* gcn2_b  = (const float*)d_in[13];
    const float* bn2_g   = (const float*)d_in[14];
    const float* bn2_b   = (const float*)d_in[15];
    const float* bn2_m   = (const float*)d_in[16];
    const float* bn2_v   = (const float*)d_in[17];
    const float* gat2_W  = (const float*)d_in[18];
    const float* gat2_as = (const float*)d_in[19];
    const float* gat2_ad = (const float*)d_in[20];
    const float* gat2_b  = (const float*)d_in[21];

    const int n = NNODES;
    const int E = in_sizes[1] / 2;
    const int* src = ei;
    const int* dst = ei + E;

    // ---- workspace carve (16B-aligned chunks) ----
    char* p = (char*)d_ws;
    float* dinv    = (float*)p; p += 50048 * 4;
    int*   degi    = (int*)p;   p += 50048 * 4;
    int*   row_ptr = (int*)p;   p += 50052 * 4;
    int*   cursor  = (int*)p;   p += 50048 * 4;
    int*   incl    = (int*)p;   p += 50048 * 4;
    int*   bsum    = (int*)p;   p += 256 * 4;
    int*   csr_src = (int*)p;   p += 800000 * 4;
    unsigned short* hbf = (unsigned short*)p; p += 9600000 * 2;  // bf16 h table [N,<=192]
    unsigned short* abf = (unsigned short*)p; p += 6400000 * 2;  // bf16 activations [N,<=128]
    unsigned short* wbf = (unsigned short*)p; p += 47616 * 2 + 64; // bf16 WT arena
    float* bufA    = (float*)p; p += 2000000 * 4;                // f32 gat2 out [N,40]
    float* alS     = (float*)p; p += 100096 * 4;
    float* alD     = (float*)p; p += 100096 * 4;
    float* selfw   = (float*)p; p += 100096 * 4;
    float* invden  = (float*)p; p += 100096 * 4;
    float* eex     = (float*)p; p += 1600000 * 4;

    unsigned short* w1T = wbf;                 // [96][128]
    unsigned short* w2T = wbf + 12288;         // [192][96]
    unsigned short* w3T = wbf + 12288 + 18432; // [96][96]
    unsigned short* w4T = wbf + 12288 + 18432 + 9216; // [80][96]

    const int B = 256;
    const int GB = nblk(n, 64);
    const int SB = nblk(n, 256);
    float* out = (float*)d_out;

    // ---- weight + input conversions (independent of CSR) ----
    k_wconv<<<nblk(128 * 96, B), B, 0, stream>>>(gcn1_W, w1T, 128, 96);
    k_wconv<<<nblk(96 * 192, B), B, 0, stream>>>(gat1_W, w2T, 96, 192);
    k_wconv<<<nblk(96 * 96, B), B, 0, stream>>>(gcn2_W, w3T, 96, 96);
    k_wconv<<<nblk(96 * 80, B), B, 0, stream>>>(gat2_W, w4T, 96, 80);
    k_xconv<<<nblk((long long)n * 16, B), B, 0, stream>>>((const float4*)x, (uint4*)abf, n * 16);

    // ---- CSR build (shared by all 4 graph layers) ----
    k_zero_deg<<<nblk(n, B), B, 0, stream>>>(degi, n);
    k_count<<<nblk(E, B), B, 0, stream>>>(dst, degi, E);
    k_scan1<<<SB, 256, 0, stream>>>(degi, incl, bsum, n);
    k_scan2<<<1, 256, 0, stream>>>(bsum, SB);
    k_scan3<<<SB, 256, 0, stream>>>(degi, incl, bsum, row_ptr, cursor, dinv, n);
    k_fill<<<nblk(E, B), B, 0, stream>>>(src, dst, cursor, csr_src, E);

    // ---- GCN1: abf[N,128] @ W[128,96] -> hbf -> gather -> BN1+relu -> abf ----
    k_gemm_mfma<128, 96><<<GB, 256, 0, stream>>>(abf, w1T, hbf, n);
    k_gcn_gather_bn8<<<nblk((long long)n * 12, B), B, 0, stream>>>(
        (const uint4*)hbf, row_ptr, csr_src, dinv, gcn1_b, bn1_g, bn1_b, bn1_m, bn1_v,
        (uint4*)abf, n, 12);

    // ---- GAT1: abf[N,96] @ W[96,192] -> hbf, H=2, C=96 ----
    k_gemm_mfma<96, 192><<<GB, 256, 0, stream>>>(abf, w2T, hbf, n);
    k_gat_logits8<<<nblk(n * 2, B), B, 0, stream>>>((const uint4*)hbf, gat1_as, gat1_ad, alS, alD, n, 96);
    k_gat_vh<<<nblk(n * 2, B), B, 0, stream>>>(row_ptr, csr_src, alS, alD, eex, selfw, invden, n, 2);
    k_gat_gather2_8<1><<<nblk((long long)n * 12, B), B, 0, stream>>>(
        (const uint4*)hbf, row_ptr, csr_src, (const float2*)eex, (const float2*)selfw,
        (const float2*)invden, gat1_b, (uint4*)abf, nullptr, n, 12, 1);

    // ---- GCN2: abf[N,96] @ W[96,96] -> hbf -> gather -> BN2+relu -> abf ----
    k_gemm_mfma<96, 96><<<GB, 256, 0, stream>>>(abf, w3T, hbf, n);
    k_gcn_gather_bn8<<<nblk((long long)n * 12, B), B, 0, stream>>>(
        (const uint4*)hbf, row_ptr, csr_src, dinv, gcn2_b, bn2_g, bn2_b, bn2_m, bn2_v,
        (uint4*)abf, n, 12);

    // ---- GAT2: abf[N,96] @ W[96,80] -> hbf, H=2, C=40 ----
    k_gemm_mfma<96, 80><<<GB, 256, 0, stream>>>(abf, w4T, hbf, n);
    k_gat_logits8<<<nblk(n * 2, B), B, 0, stream>>>((const uint4*)hbf, gat2_as, gat2_ad, alS, alD, n, 40);
    k_gat_vh<<<nblk(n * 2, B), B, 0, stream>>>(row_ptr, csr_src, alS, alD, eex, selfw, invden, n, 2);
    k_gat_gather2_8<0><<<nblk((long long)n * 5, B), B, 0, stream>>>(
        (const uint4*)hbf, row_ptr, csr_src, (const float2*)eex, (const float2*)selfw,
        (const float2*)invden, gat2_b, nullptr, (float4*)bufA, n, 5, 0);

    // ---- log_softmax -> d_out ----
    k_logsoftmax40<<<nblk(n, B), B, 0, stream>>>(bufA, out, n);
}